// Round 3
// baseline (990.130 us; speedup 1.0000x reference)
//
#include <hip/hip_runtime.h>

#define NEG_SLOPE 0.2f
#define EPSV 1e-16f

// ---------------------------------------------------------------------------
// CSR build (by destination node), self-loops appended after the E real edges
// ---------------------------------------------------------------------------
__global__ __launch_bounds__(256)
void count_kernel(const int* __restrict__ ei, int* __restrict__ deg, int E, int n) {
    int i = blockIdx.x * blockDim.x + threadIdx.x;
    int M = E + n;
    if (i >= M) return;
    int d = (i < E) ? ei[E + i] : (i - E);
    atomicAdd(&deg[d], 1);
}

__global__ __launch_bounds__(1024)
void scan_kernel(const int* __restrict__ deg, int* __restrict__ indptr, int n) {
    __shared__ int wsum[16];
    __shared__ int carry_s;
    const int t = threadIdx.x;
    const int lane = t & 63;
    const int w = t >> 6;
    if (t == 0) carry_s = 0;
    __syncthreads();
    for (int base = 0; base < n; base += 1024) {
        int i = base + t;
        int v = (i < n) ? deg[i] : 0;
        int s = v;
        #pragma unroll
        for (int off = 1; off < 64; off <<= 1) {
            int u = __shfl_up(s, off);
            if (lane >= off) s += u;
        }
        if (lane == 63) wsum[w] = s;
        __syncthreads();
        if (w == 0 && lane < 16) {
            int ws_ = wsum[lane];
            #pragma unroll
            for (int off = 1; off < 16; off <<= 1) {
                int u = __shfl_up(ws_, off);
                if (lane >= off) ws_ += u;
            }
            wsum[lane] = ws_;
        }
        __syncthreads();
        int woff = (w > 0) ? wsum[w - 1] : 0;
        int total = wsum[15];
        int carry = carry_s;
        if (i < n) indptr[i + 1] = carry + woff + s;
        __syncthreads();
        if (t == 0) carry_s = carry + total;
        __syncthreads();
    }
    if (t == 0) indptr[0] = 0;
}

__global__ __launch_bounds__(256)
void scatter_kernel(const int* __restrict__ ei, int* __restrict__ cursor,
                    int* __restrict__ csr_src, int E, int n) {
    int i = blockIdx.x * blockDim.x + threadIdx.x;
    int M = E + n;
    if (i >= M) return;
    int s, d;
    if (i < E) { s = ei[i]; d = ei[E + i]; }
    else       { s = i - E; d = i - E; }
    int pos = atomicAdd(&cursor[d], 1);
    csr_src[pos] = s;
}

// ---------------------------------------------------------------------------
// fp32 GEMM: C[M,N] = A[M,K] @ B[K,N].  128 x TBN tile, 256 threads,
// 8x8 (or 8x4) micro-tile in 2x2 sub-blocks 64 apart (bank-conflict free).
// ---------------------------------------------------------------------------
template<int TBN>
__global__ __launch_bounds__(256)
void gemm_kernel(const float* __restrict__ A, const float* __restrict__ B,
                 float* __restrict__ C, int M, int K, int N) {
    constexpr int TBM = 128, TBK = 16;
    constexpr int NC = TBN / 64;                 // 2 for TBN=128, 1 for TBN=64
    __shared__ float As[TBK][TBM + 4];           // 132 floats: 16B-aligned rows
    __shared__ float Bs[TBK][TBN + 4];
    const int tid = threadIdx.x;
    const int tr = tid >> 4;     // 0..15
    const int tc = tid & 15;     // 0..15
    const int row0 = blockIdx.x * TBM;
    const int col0 = blockIdx.y * TBN;
    float acc[2][NC][4][4] = {};
    for (int k0 = 0; k0 < K; k0 += TBK) {
        #pragma unroll
        for (int it = 0; it < (TBM * TBK) / 256; ++it) {   // 8
            int idx = tid + it * 256;
            int r = idx >> 4;
            int kk = idx & 15;
            int gr = row0 + r;
            As[kk][r] = (gr < M) ? A[(long)gr * K + k0 + kk] : 0.f;
        }
        #pragma unroll
        for (int it = 0; it < (TBK * TBN) / 256; ++it) {   // 8 or 4
            int idx = tid + it * 256;
            int kk = idx / TBN;
            int c = idx % TBN;
            Bs[kk][c] = B[(long)(k0 + kk) * N + col0 + c];
        }
        __syncthreads();
        #pragma unroll
        for (int kk = 0; kk < TBK; ++kk) {
            float a[2][4], b[NC][4];
            #pragma unroll
            for (int ri = 0; ri < 2; ++ri)
                #pragma unroll
                for (int i = 0; i < 4; ++i)
                    a[ri][i] = As[kk][ri * 64 + tr * 4 + i];
            #pragma unroll
            for (int ci = 0; ci < NC; ++ci)
                #pragma unroll
                for (int j = 0; j < 4; ++j)
                    b[ci][j] = Bs[kk][ci * 64 + tc * 4 + j];
            #pragma unroll
            for (int ri = 0; ri < 2; ++ri)
                #pragma unroll
                for (int ci = 0; ci < NC; ++ci)
                    #pragma unroll
                    for (int i = 0; i < 4; ++i)
                        #pragma unroll
                        for (int j = 0; j < 4; ++j)
                            acc[ri][ci][i][j] += a[ri][i] * b[ci][j];
        }
        __syncthreads();
    }
    #pragma unroll
    for (int ri = 0; ri < 2; ++ri) {
        #pragma unroll
        for (int i = 0; i < 4; ++i) {
            int gr = row0 + ri * 64 + tr * 4 + i;
            if (gr < M) {
                #pragma unroll
                for (int ci = 0; ci < NC; ++ci) {
                    float4 v = make_float4(acc[ri][ci][i][0], acc[ri][ci][i][1],
                                           acc[ri][ci][i][2], acc[ri][ci][i][3]);
                    *reinterpret_cast<float4*>(&C[(long)gr * N + col0 + ci * 64 + tc * 4]) = v;
                }
            }
        }
    }
}

// ---------------------------------------------------------------------------
// alpha over rows of 64 channels: h is [R][64] with R = N*H, row = node*H+hd.
// Wave handles 4 rows (slot = lane>>4), float4 dot + 16-lane-group reduction.
// ---------------------------------------------------------------------------
__global__ __launch_bounds__(256)
void alpha_kernel(const float* __restrict__ h, const float* __restrict__ a_src,
                  const float* __restrict__ a_dst, float* __restrict__ asrc,
                  float* __restrict__ adst, int R, int Hmask) {
    const int lane = threadIdx.x & 63;
    const int slot = lane >> 4;
    const int sub  = lane & 15;
    const int row = (((blockIdx.x * blockDim.x + threadIdx.x) >> 6) << 2) + slot;
    if (row >= R) return;
    const int hd = row & Hmask;          // H is a power of 2
    float4 v  = *reinterpret_cast<const float4*>(h + (long)row * 64 + 4 * sub);
    float4 cs = *reinterpret_cast<const float4*>(a_src + hd * 64 + 4 * sub);
    float4 cd = *reinterpret_cast<const float4*>(a_dst + hd * 64 + 4 * sub);
    float s = v.x * cs.x + v.y * cs.y + v.z * cs.z + v.w * cs.w;
    float d = v.x * cd.x + v.y * cd.y + v.z * cd.z + v.w * cd.w;
    #pragma unroll
    for (int off = 1; off < 16; off <<= 1) {
        s += __shfl_xor(s, off);
        d += __shfl_xor(d, off);
    }
    if (sub == 0) {
        asrc[row] = s;
        adst[row] = d;
    }
}

// ---------------------------------------------------------------------------
// Aggregate, H=4 (HC=256): ONE wave per node, all 4 heads together.
// Pass A: 16 edges x 4 heads lane-parallel (lane = head*16 + edge-slot),
//   16-lane-group shuffle max/sum, exp -> per-wave LDS.
// Pass B: full 1KB row gather per edge (float4/lane), 4 FMAs/lane, unroll x4.
// Online rescale across chunks.
// ---------------------------------------------------------------------------
__global__ __launch_bounds__(256)
void aggregate4_kernel(const float* __restrict__ h, const float* __restrict__ asrc,
                       const float* __restrict__ adst, const int* __restrict__ indptr,
                       const int* __restrict__ csr_src, const float* __restrict__ bias,
                       float* __restrict__ out, int n, int apply_elu) {
    __shared__ int   sOff[4][16];
    __shared__ float sEx[4][4][16];     // [wave][head][edge-slot]
    const int node = (blockIdx.x * blockDim.x + threadIdx.x) >> 6;
    const int lane = threadIdx.x & 63;
    const int w    = threadIdx.x >> 6;
    if (node >= n) return;
    const int hd   = lane >> 4;
    const int eidx = lane & 15;
    const int beg = indptr[node], end = indptr[node + 1];
    const float ad = adst[node * 4 + hd];
    const float* __restrict__ hrow = h + 4 * lane;   // + s*256 per edge

    float m = -3.4e38f, sum_ex = 0.f;
    float ax = 0.f, ay = 0.f, az = 0.f, aw = 0.f;
    for (int cb = beg; cb < end; cb += 16) {
        const int cnt = min(16, end - cb);
        // ---- pass A ----
        int s = 0;
        float e = -3.4e38f;
        if (eidx < cnt) {
            s = csr_src[cb + eidx];
            e = asrc[s * 4 + hd] + ad;
            e = e > 0.f ? e : NEG_SLOPE * e;
        }
        float cm = e;
        #pragma unroll
        for (int off = 1; off < 16; off <<= 1) cm = fmaxf(cm, __shfl_xor(cm, off));
        const float nm = fmaxf(m, cm);
        const float scale = __expf(m - nm);      // 0 on first chunk
        const float ex = (eidx < cnt) ? __expf(e - nm) : 0.f;
        float cssum = ex;
        #pragma unroll
        for (int off = 1; off < 16; off <<= 1) cssum += __shfl_xor(cssum, off);
        sum_ex = sum_ex * scale + cssum;
        ax *= scale; ay *= scale; az *= scale; aw *= scale;
        m = nm;
        if (lane < 16) sOff[w][eidx] = s << 8;   // element offset s*256
        sEx[w][hd][eidx] = ex;
        // ---- pass B: gather full rows, unrolled x4 ----
        int i = 0;
        for (; i + 3 < cnt; i += 4) {
            int o0 = sOff[w][i],     o1 = sOff[w][i + 1];
            int o2 = sOff[w][i + 2], o3 = sOff[w][i + 3];
            float e0 = sEx[w][hd][i],     e1 = sEx[w][hd][i + 1];
            float e2 = sEx[w][hd][i + 2], e3 = sEx[w][hd][i + 3];
            float4 v0 = *reinterpret_cast<const float4*>(hrow + o0);
            float4 v1 = *reinterpret_cast<const float4*>(hrow + o1);
            float4 v2 = *reinterpret_cast<const float4*>(hrow + o2);
            float4 v3 = *reinterpret_cast<const float4*>(hrow + o3);
            ax += e0 * v0.x + e1 * v1.x + e2 * v2.x + e3 * v3.x;
            ay += e0 * v0.y + e1 * v1.y + e2 * v2.y + e3 * v3.y;
            az += e0 * v0.z + e1 * v1.z + e2 * v2.z + e3 * v3.z;
            aw += e0 * v0.w + e1 * v1.w + e2 * v2.w + e3 * v3.w;
        }
        for (; i < cnt; ++i) {
            int o = sOff[w][i];
            float ee = sEx[w][hd][i];
            float4 v = *reinterpret_cast<const float4*>(hrow + o);
            ax += ee * v.x; ay += ee * v.y; az += ee * v.z; aw += ee * v.w;
        }
    }
    const float inv = 1.f / (sum_ex + EPSV);
    float4 b4 = *reinterpret_cast<const float4*>(bias + 4 * lane);
    float ox = ax * inv + b4.x;
    float oy = ay * inv + b4.y;
    float oz = az * inv + b4.z;
    float ow = aw * inv + b4.w;
    if (apply_elu) {
        ox = ox > 0.f ? ox : expm1f(ox);
        oy = oy > 0.f ? oy : expm1f(oy);
        oz = oz > 0.f ? oz : expm1f(oz);
        ow = ow > 0.f ? ow : expm1f(ow);
    }
    float4 o4 = make_float4(ox, oy, oz, ow);
    *reinterpret_cast<float4*>(out + (long)node * 256 + 4 * lane) = o4;
}

// ---------------------------------------------------------------------------
// Aggregate, generic per-(node,head) (used for H=1). Wave = 64 lanes = channels.
// ---------------------------------------------------------------------------
__global__ __launch_bounds__(256)
void aggregate_kernel(const float* __restrict__ h, const float* __restrict__ asrc,
                      const float* __restrict__ adst, const int* __restrict__ indptr,
                      const int* __restrict__ csr_src, const float* __restrict__ bias,
                      float* __restrict__ out, int n, int H, int apply_elu) {
    __shared__ int   sInd[4][64];
    __shared__ float sEx[4][64];
    const int wid  = (blockIdx.x * blockDim.x + threadIdx.x) >> 6;
    const int lane = threadIdx.x & 63;
    const int w    = threadIdx.x >> 6;
    const int node = wid / H;
    const int hd   = wid - node * H;
    if (node >= n) return;
    const int HC = H * 64;
    const int beg = indptr[node];
    const int end = indptr[node + 1];
    const float ad = adst[node * H + hd];
    const float* __restrict__ hh = h + hd * 64 + lane;

    float m = -3.4e38f, sum_ex = 0.f, acc = 0.f;
    for (int cb = beg; cb < end; cb += 64) {
        const int cnt = min(64, end - cb);
        int s = 0;
        float e = -3.4e38f;
        if (lane < cnt) {
            s = csr_src[cb + lane];
            e = asrc[s * H + hd] + ad;
            e = e > 0.f ? e : NEG_SLOPE * e;
        }
        float cm = e;
        #pragma unroll
        for (int off = 32; off > 0; off >>= 1) cm = fmaxf(cm, __shfl_xor(cm, off));
        const float nm = fmaxf(m, cm);
        const float scale = __expf(m - nm);
        const float ex = (lane < cnt) ? __expf(e - nm) : 0.f;
        float cs = ex;
        #pragma unroll
        for (int off = 32; off > 0; off >>= 1) cs += __shfl_xor(cs, off);
        sum_ex = sum_ex * scale + cs;
        acc *= scale;
        m = nm;
        sInd[w][lane] = s;
        sEx[w][lane]  = ex;
        int i = 0;
        for (; i + 3 < cnt; i += 4) {
            int s0 = sInd[w][i],     s1 = sInd[w][i + 1];
            int s2 = sInd[w][i + 2], s3 = sInd[w][i + 3];
            float e0 = sEx[w][i],     e1 = sEx[w][i + 1];
            float e2 = sEx[w][i + 2], e3 = sEx[w][i + 3];
            float v0 = hh[(long)s0 * HC];
            float v1 = hh[(long)s1 * HC];
            float v2 = hh[(long)s2 * HC];
            float v3 = hh[(long)s3 * HC];
            acc += e0 * v0;
            acc += e1 * v1;
            acc += e2 * v2;
            acc += e3 * v3;
        }
        for (; i < cnt; ++i)
            acc += sEx[w][i] * hh[(long)sInd[w][i] * HC];
    }
    float o = acc / (sum_ex + EPSV) + bias[hd * 64 + lane];
    if (apply_elu) o = o > 0.f ? o : expm1f(o);
    out[(long)node * HC + hd * 64 + lane] = o;
}

// ---------------------------------------------------------------------------
// Global mean pool (batch is sorted) + classifier
// ---------------------------------------------------------------------------
constexpr int POOL_CHUNK = 128;

__global__ __launch_bounds__(64)
void pool_kernel(const float* __restrict__ h, const int* __restrict__ batch,
                 float* __restrict__ sums, int* __restrict__ counts, int n) {
    int lane = threadIdx.x;
    int start = blockIdx.x * POOL_CHUNK;
    if (start >= n) return;
    int end = min(start + POOL_CHUNK, n);
    int gcur = batch[start];
    float acc = 0.f;
    int run = 0;
    for (int i = start; i < end; ++i) {
        int g = batch[i];
        if (g != gcur) {
            atomicAdd(&sums[gcur * 64 + lane], acc);
            if (lane == 0) atomicAdd(&counts[gcur], run);
            acc = 0.f; run = 0; gcur = g;
        }
        acc += h[(long)i * 64 + lane];
        ++run;
    }
    atomicAdd(&sums[gcur * 64 + lane], acc);
    if (lane == 0) atomicAdd(&counts[gcur], run);
}

__global__ void classify_kernel(const float* __restrict__ sums, const int* __restrict__ counts,
                                const float* __restrict__ Wc, const float* __restrict__ bc,
                                float* __restrict__ out, int G) {
    int t = threadIdx.x;
    if (t >= G * 10) return;
    int g = t / 10, o = t - g * 10;
    int c_ = counts[g];
    float inv = 1.f / (float)(c_ > 1 ? c_ : 1);
    float acc = bc[o];
    for (int c = 0; c < 64; ++c)
        acc += sums[g * 64 + c] * inv * Wc[c * 10 + o];
    out[t] = acc;
}

// ---------------------------------------------------------------------------
extern "C" void kernel_launch(void* const* d_in, const int* in_sizes, int n_in,
                              void* d_out, int out_size, void* d_ws, size_t ws_size,
                              hipStream_t stream) {
    const float* x   = (const float*)d_in[0];
    const int*   ei  = (const int*)d_in[1];
    const int*   bat = (const int*)d_in[2];
    const float* W1  = (const float*)d_in[3];
    const float* as1 = (const float*)d_in[4];
    const float* ad1 = (const float*)d_in[5];
    const float* b1  = (const float*)d_in[6];
    const float* W2  = (const float*)d_in[7];
    const float* as2 = (const float*)d_in[8];
    const float* ad2 = (const float*)d_in[9];
    const float* b2  = (const float*)d_in[10];
    const float* W3  = (const float*)d_in[11];
    const float* as3 = (const float*)d_in[12];
    const float* ad3 = (const float*)d_in[13];
    const float* b3  = (const float*)d_in[14];
    const float* Wc  = (const float*)d_in[15];
    const float* bc  = (const float*)d_in[16];
    float* out = (float*)d_out;

    const int N = in_sizes[2];          // 50000 nodes
    const int E = in_sizes[1] / 2;      // 800000 edges
    const int M = E + N;                // + self loops
    const int IN_C = in_sizes[0] / N;   // 128
    const int G = out_size / 10;        // 64 graphs

    // -------- workspace carve (256B aligned) --------
    char* p = (char*)d_ws;
    auto carve = [&](size_t bytes) -> void* {
        void* r = (void*)p;
        p += (bytes + 255) & ~(size_t)255;
        return r;
    };
    float* hA   = (float*)carve((size_t)N * 256 * 4);
    float* hB   = (float*)carve((size_t)N * 256 * 4);
    float* asrc = (float*)carve((size_t)N * 4 * 4);
    float* adst = (float*)carve((size_t)N * 4 * 4);
    float* sums = (float*)carve((size_t)G * 64 * 4);
    int*   cnts = (int*)carve((size_t)G * 4);
    int*   deg  = (int*)carve((size_t)N * 4);      // reused as scatter cursor
    int*   iptr = (int*)carve((size_t)(N + 1) * 4);
    int*   csr  = (int*)carve((size_t)M * 4);
    (void)ws_size; (void)n_in;

    // -------- CSR build (shared by all 3 layers) --------
    hipMemsetAsync(deg, 0, (size_t)N * 4, stream);
    count_kernel<<<(M + 255) / 256, 256, 0, stream>>>(ei, deg, E, N);
    scan_kernel<<<1, 1024, 0, stream>>>(deg, iptr, N);
    hipMemcpyAsync(deg, iptr, (size_t)N * 4, hipMemcpyDeviceToDevice, stream);
    scatter_kernel<<<(M + 255) / 256, 256, 0, stream>>>(ei, deg, csr, E, N);

    // -------- layer 1: x[N,128] -> hB[N,256] --------
    {
        dim3 grid((N + 127) / 128, 256 / 128);
        gemm_kernel<128><<<grid, 256, 0, stream>>>(x, W1, hA, N, IN_C, 256);
    }
    alpha_kernel<<<(N * 4 + 15) / 16, 256, 0, stream>>>(hA, as1, ad1, asrc, adst, N * 4, 3);
    aggregate4_kernel<<<(N + 3) / 4, 256, 0, stream>>>(hA, asrc, adst, iptr, csr, b1, hB, N, 1);

    // -------- layer 2: hB[N,256] -> hB[N,256] --------
    {
        dim3 grid((N + 127) / 128, 256 / 128);
        gemm_kernel<128><<<grid, 256, 0, stream>>>(hB, W2, hA, N, 256, 256);
    }
    alpha_kernel<<<(N * 4 + 15) / 16, 256, 0, stream>>>(hA, as2, ad2, asrc, adst, N * 4, 3);
    aggregate4_kernel<<<(N + 3) / 4, 256, 0, stream>>>(hA, asrc, adst, iptr, csr, b2, hB, N, 1);

    // -------- layer 3: hB[N,256] -> hB[N,64] (1 head, no ELU) --------
    {
        dim3 grid((N + 127) / 128, 1);
        gemm_kernel<64><<<grid, 256, 0, stream>>>(hB, W3, hA, N, 256, 64);
    }
    alpha_kernel<<<(N + 15) / 16, 256, 0, stream>>>(hA, as3, ad3, asrc, adst, N, 0);
    aggregate_kernel<<<(N + 3) / 4, 256, 0, stream>>>(hA, asrc, adst, iptr, csr, b3, hB, N, 1, 0);

    // -------- pool + classify --------
    hipMemsetAsync(sums, 0, (size_t)G * 64 * 4, stream);
    hipMemsetAsync(cnts, 0, (size_t)G * 4, stream);
    pool_kernel<<<(N + POOL_CHUNK - 1) / POOL_CHUNK, 64, 0, stream>>>(hB, bat, sums, cnts, N);
    classify_kernel<<<1, 640, 0, stream>>>(sums, cnts, Wc, bc, out, G);
}

// Round 4
// 778.960 us; speedup vs baseline: 1.2711x; 1.2711x over previous
//
#include <hip/hip_runtime.h>

#define NEG_SLOPE 0.2f
#define EPSV 1e-16f

// ---------------------------------------------------------------------------
// CSR build (by destination node), self-loops appended after the E real edges
// ---------------------------------------------------------------------------
__global__ __launch_bounds__(256)
void count_kernel(const int* __restrict__ ei, int* __restrict__ deg, int E, int n) {
    int i = blockIdx.x * blockDim.x + threadIdx.x;
    int M = E + n;
    if (i >= M) return;
    int d = (i < E) ? ei[E + i] : (i - E);
    atomicAdd(&deg[d], 1);
}

__global__ __launch_bounds__(1024)
void scan_kernel(const int* __restrict__ deg, int* __restrict__ indptr, int n) {
    __shared__ int wsum[16];
    __shared__ int carry_s;
    const int t = threadIdx.x;
    const int lane = t & 63;
    const int w = t >> 6;
    if (t == 0) carry_s = 0;
    __syncthreads();
    for (int base = 0; base < n; base += 1024) {
        int i = base + t;
        int v = (i < n) ? deg[i] : 0;
        int s = v;
        #pragma unroll
        for (int off = 1; off < 64; off <<= 1) {
            int u = __shfl_up(s, off);
            if (lane >= off) s += u;
        }
        if (lane == 63) wsum[w] = s;
        __syncthreads();
        if (w == 0 && lane < 16) {
            int ws_ = wsum[lane];
            #pragma unroll
            for (int off = 1; off < 16; off <<= 1) {
                int u = __shfl_up(ws_, off);
                if (lane >= off) ws_ += u;
            }
            wsum[lane] = ws_;
        }
        __syncthreads();
        int woff = (w > 0) ? wsum[w - 1] : 0;
        int total = wsum[15];
        int carry = carry_s;
        if (i < n) indptr[i + 1] = carry + woff + s;
        __syncthreads();
        if (t == 0) carry_s = carry + total;
        __syncthreads();
    }
    if (t == 0) indptr[0] = 0;
}

__global__ __launch_bounds__(256)
void scatter_kernel(const int* __restrict__ ei, int* __restrict__ cursor,
                    int* __restrict__ csr_src, int E, int n) {
    int i = blockIdx.x * blockDim.x + threadIdx.x;
    int M = E + n;
    if (i >= M) return;
    int s, d;
    if (i < E) { s = ei[i]; d = ei[E + i]; }
    else       { s = i - E; d = i - E; }
    int pos = atomicAdd(&cursor[d], 1);
    csr_src[pos] = s;
}

// ---------------------------------------------------------------------------
// fp32 GEMM (128x64 tile, 256 threads, 8x4 acc) with FUSED alpha epilogue.
// BN=64 == one head's channels, so alpha_src/dst for head col0/64 are fully
// computable in-block:  asrc[row*H+hd] = sum_c C[row,hd*64+c]*a_src[hd,c].
// ---------------------------------------------------------------------------
__global__ __launch_bounds__(256)
void gemm_alpha_kernel(const float* __restrict__ A, const float* __restrict__ B,
                       float* __restrict__ C,
                       const float* __restrict__ a_src, const float* __restrict__ a_dst,
                       float* __restrict__ asrc, float* __restrict__ adst,
                       int M, int K, int N, int H) {
    constexpr int TBM = 128, TBN = 64, TBK = 16;
    __shared__ float As[TBK][TBM + 4];   // 132 floats/row, 16B-aligned rows
    __shared__ float Bs[TBK][TBN + 4];   // 68 floats/row,  16B-aligned rows
    const int tid = threadIdx.x;
    const int tr = tid >> 4;     // 0..15
    const int tc = tid & 15;     // 0..15
    const int row0 = blockIdx.x * TBM;
    const int col0 = blockIdx.y * TBN;
    float acc[8][4] = {};
    for (int k0 = 0; k0 < K; k0 += TBK) {
        // ---- stage A (float4 loads, transposed scatter to LDS) ----
        #pragma unroll
        for (int it = 0; it < 2; ++it) {
            int idx = tid + it * 256;        // 0..511 float4 slots
            int r = idx >> 2;                // 0..127
            int q = idx & 3;                 // which float4 in the 16-wide row
            int gr = row0 + r;
            float4 v = make_float4(0.f, 0.f, 0.f, 0.f);
            if (gr < M)
                v = *reinterpret_cast<const float4*>(A + (long)gr * K + k0 + 4 * q);
            As[4 * q + 0][r] = v.x;
            As[4 * q + 1][r] = v.y;
            As[4 * q + 2][r] = v.z;
            As[4 * q + 3][r] = v.w;
        }
        // ---- stage B (float4 load + b128 LDS write) ----
        {
            int kk = tid >> 4;               // 0..15
            int c4 = tid & 15;               // float4 col
            float4 v = *reinterpret_cast<const float4*>(B + (long)(k0 + kk) * N + col0 + 4 * c4);
            *reinterpret_cast<float4*>(&Bs[kk][4 * c4]) = v;
        }
        __syncthreads();
        #pragma unroll
        for (int kk = 0; kk < TBK; ++kk) {
            float4 a0 = *reinterpret_cast<const float4*>(&As[kk][tr * 8]);
            float4 a1 = *reinterpret_cast<const float4*>(&As[kk][tr * 8 + 4]);
            float4 b0 = *reinterpret_cast<const float4*>(&Bs[kk][tc * 4]);
            float av[8] = {a0.x, a0.y, a0.z, a0.w, a1.x, a1.y, a1.z, a1.w};
            #pragma unroll
            for (int i = 0; i < 8; ++i) {
                acc[i][0] += av[i] * b0.x;
                acc[i][1] += av[i] * b0.y;
                acc[i][2] += av[i] * b0.z;
                acc[i][3] += av[i] * b0.w;
            }
        }
        __syncthreads();
    }
    // ---- C store ----
    #pragma unroll
    for (int i = 0; i < 8; ++i) {
        int gr = row0 + tr * 8 + i;
        if (gr < M) {
            float4 v = make_float4(acc[i][0], acc[i][1], acc[i][2], acc[i][3]);
            *reinterpret_cast<float4*>(&C[(long)gr * N + col0 + tc * 4]) = v;
        }
    }
    // ---- fused alpha epilogue (head hd = col0/64) ----
    const int hd = col0 >> 6;
    float4 awS = *reinterpret_cast<const float4*>(a_src + col0 + tc * 4);
    float4 awD = *reinterpret_cast<const float4*>(a_dst + col0 + tc * 4);
    #pragma unroll
    for (int i = 0; i < 8; ++i) {
        float s = acc[i][0] * awS.x + acc[i][1] * awS.y + acc[i][2] * awS.z + acc[i][3] * awS.w;
        float d = acc[i][0] * awD.x + acc[i][1] * awD.y + acc[i][2] * awD.z + acc[i][3] * awD.w;
        #pragma unroll
        for (int off = 1; off < 16; off <<= 1) {
            s += __shfl_xor(s, off);
            d += __shfl_xor(d, off);
        }
        int gr = row0 + tr * 8 + i;
        if (tc == 0 && gr < M) {
            asrc[gr * H + hd] = s;
            adst[gr * H + hd] = d;
        }
    }
}

// ---------------------------------------------------------------------------
// Aggregate, H=4 (HC=256): ONE wave per node, all 4 heads together.
// ---------------------------------------------------------------------------
__global__ __launch_bounds__(256)
void aggregate4_kernel(const float* __restrict__ h, const float* __restrict__ asrc,
                       const float* __restrict__ adst, const int* __restrict__ indptr,
                       const int* __restrict__ csr_src, const float* __restrict__ bias,
                       float* __restrict__ out, int n, int apply_elu) {
    __shared__ int   sOff[4][16];
    __shared__ float sEx[4][4][16];     // [wave][head][edge-slot]
    const int node = (blockIdx.x * blockDim.x + threadIdx.x) >> 6;
    const int lane = threadIdx.x & 63;
    const int w    = threadIdx.x >> 6;
    if (node >= n) return;
    const int hd   = lane >> 4;
    const int eidx = lane & 15;
    const int beg = indptr[node], end = indptr[node + 1];
    const float ad = adst[node * 4 + hd];
    const float* __restrict__ hrow = h + 4 * lane;   // + s*256 per edge

    float m = -3.4e38f, sum_ex = 0.f;
    float ax = 0.f, ay = 0.f, az = 0.f, aw = 0.f;
    for (int cb = beg; cb < end; cb += 16) {
        const int cnt = min(16, end - cb);
        // ---- pass A ----
        int s = 0;
        float e = -3.4e38f;
        if (eidx < cnt) {
            s = csr_src[cb + eidx];
            e = asrc[s * 4 + hd] + ad;
            e = e > 0.f ? e : NEG_SLOPE * e;
        }
        float cm = e;
        #pragma unroll
        for (int off = 1; off < 16; off <<= 1) cm = fmaxf(cm, __shfl_xor(cm, off));
        const float nm = fmaxf(m, cm);
        const float scale = __expf(m - nm);      // 0 on first chunk
        const float ex = (eidx < cnt) ? __expf(e - nm) : 0.f;
        float cssum = ex;
        #pragma unroll
        for (int off = 1; off < 16; off <<= 1) cssum += __shfl_xor(cssum, off);
        sum_ex = sum_ex * scale + cssum;
        ax *= scale; ay *= scale; az *= scale; aw *= scale;
        m = nm;
        if (lane < 16) sOff[w][eidx] = s << 8;   // element offset s*256
        sEx[w][hd][eidx] = ex;
        // ---- pass B: gather full rows, unrolled x4 ----
        int i = 0;
        for (; i + 3 < cnt; i += 4) {
            int o0 = sOff[w][i],     o1 = sOff[w][i + 1];
            int o2 = sOff[w][i + 2], o3 = sOff[w][i + 3];
            float e0 = sEx[w][hd][i],     e1 = sEx[w][hd][i + 1];
            float e2 = sEx[w][hd][i + 2], e3 = sEx[w][hd][i + 3];
            float4 v0 = *reinterpret_cast<const float4*>(hrow + o0);
            float4 v1 = *reinterpret_cast<const float4*>(hrow + o1);
            float4 v2 = *reinterpret_cast<const float4*>(hrow + o2);
            float4 v3 = *reinterpret_cast<const float4*>(hrow + o3);
            ax += e0 * v0.x + e1 * v1.x + e2 * v2.x + e3 * v3.x;
            ay += e0 * v0.y + e1 * v1.y + e2 * v2.y + e3 * v3.y;
            az += e0 * v0.z + e1 * v1.z + e2 * v2.z + e3 * v3.z;
            aw += e0 * v0.w + e1 * v1.w + e2 * v2.w + e3 * v3.w;
        }
        for (; i < cnt; ++i) {
            int o = sOff[w][i];
            float ee = sEx[w][hd][i];
            float4 v = *reinterpret_cast<const float4*>(hrow + o);
            ax += ee * v.x; ay += ee * v.y; az += ee * v.z; aw += ee * v.w;
        }
    }
    const float inv = 1.f / (sum_ex + EPSV);
    float4 b4 = *reinterpret_cast<const float4*>(bias + 4 * lane);
    float ox = ax * inv + b4.x;
    float oy = ay * inv + b4.y;
    float oz = az * inv + b4.z;
    float ow = aw * inv + b4.w;
    if (apply_elu) {
        ox = ox > 0.f ? ox : expm1f(ox);
        oy = oy > 0.f ? oy : expm1f(oy);
        oz = oz > 0.f ? oz : expm1f(oz);
        ow = ow > 0.f ? ow : expm1f(ow);
    }
    float4 o4 = make_float4(ox, oy, oz, ow);
    *reinterpret_cast<float4*>(out + (long)node * 256 + 4 * lane) = o4;
}

// ---------------------------------------------------------------------------
// Aggregate, generic per-(node,head) (used for H=1). Wave = 64 lanes = channels.
// ---------------------------------------------------------------------------
__global__ __launch_bounds__(256)
void aggregate_kernel(const float* __restrict__ h, const float* __restrict__ asrc,
                      const float* __restrict__ adst, const int* __restrict__ indptr,
                      const int* __restrict__ csr_src, const float* __restrict__ bias,
                      float* __restrict__ out, int n, int H, int apply_elu) {
    __shared__ int   sInd[4][64];
    __shared__ float sEx[4][64];
    const int wid  = (blockIdx.x * blockDim.x + threadIdx.x) >> 6;
    const int lane = threadIdx.x & 63;
    const int w    = threadIdx.x >> 6;
    const int node = wid / H;
    const int hd   = wid - node * H;
    if (node >= n) return;
    const int HC = H * 64;
    const int beg = indptr[node];
    const int end = indptr[node + 1];
    const float ad = adst[node * H + hd];
    const float* __restrict__ hh = h + hd * 64 + lane;

    float m = -3.4e38f, sum_ex = 0.f, acc = 0.f;
    for (int cb = beg; cb < end; cb += 64) {
        const int cnt = min(64, end - cb);
        int s = 0;
        float e = -3.4e38f;
        if (lane < cnt) {
            s = csr_src[cb + lane];
            e = asrc[s * H + hd] + ad;
            e = e > 0.f ? e : NEG_SLOPE * e;
        }
        float cm = e;
        #pragma unroll
        for (int off = 32; off > 0; off >>= 1) cm = fmaxf(cm, __shfl_xor(cm, off));
        const float nm = fmaxf(m, cm);
        const float scale = __expf(m - nm);
        const float ex = (lane < cnt) ? __expf(e - nm) : 0.f;
        float cs = ex;
        #pragma unroll
        for (int off = 32; off > 0; off >>= 1) cs += __shfl_xor(cs, off);
        sum_ex = sum_ex * scale + cs;
        acc *= scale;
        m = nm;
        sInd[w][lane] = s;
        sEx[w][lane]  = ex;
        int i = 0;
        for (; i + 3 < cnt; i += 4) {
            int s0 = sInd[w][i],     s1 = sInd[w][i + 1];
            int s2 = sInd[w][i + 2], s3 = sInd[w][i + 3];
            float e0 = sEx[w][i],     e1 = sEx[w][i + 1];
            float e2 = sEx[w][i + 2], e3 = sEx[w][i + 3];
            float v0 = hh[(long)s0 * HC];
            float v1 = hh[(long)s1 * HC];
            float v2 = hh[(long)s2 * HC];
            float v3 = hh[(long)s3 * HC];
            acc += e0 * v0;
            acc += e1 * v1;
            acc += e2 * v2;
            acc += e3 * v3;
        }
        for (; i < cnt; ++i)
            acc += sEx[w][i] * hh[(long)sInd[w][i] * HC];
    }
    float o = acc / (sum_ex + EPSV) + bias[hd * 64 + lane];
    if (apply_elu) o = o > 0.f ? o : expm1f(o);
    out[(long)node * HC + hd * 64 + lane] = o;
}

// ---------------------------------------------------------------------------
// Global mean pool (batch is sorted) + classifier
// ---------------------------------------------------------------------------
constexpr int POOL_CHUNK = 128;

__global__ __launch_bounds__(64)
void pool_kernel(const float* __restrict__ h, const int* __restrict__ batch,
                 float* __restrict__ sums, int* __restrict__ counts, int n) {
    int lane = threadIdx.x;
    int start = blockIdx.x * POOL_CHUNK;
    if (start >= n) return;
    int end = min(start + POOL_CHUNK, n);
    int gcur = batch[start];
    float acc = 0.f;
    int run = 0;
    for (int i = start; i < end; ++i) {
        int g = batch[i];
        if (g != gcur) {
            atomicAdd(&sums[gcur * 64 + lane], acc);
            if (lane == 0) atomicAdd(&counts[gcur], run);
            acc = 0.f; run = 0; gcur = g;
        }
        acc += h[(long)i * 64 + lane];
        ++run;
    }
    atomicAdd(&sums[gcur * 64 + lane], acc);
    if (lane == 0) atomicAdd(&counts[gcur], run);
}

__global__ void classify_kernel(const float* __restrict__ sums, const int* __restrict__ counts,
                                const float* __restrict__ Wc, const float* __restrict__ bc,
                                float* __restrict__ out, int G) {
    int t = threadIdx.x;
    if (t >= G * 10) return;
    int g = t / 10, o = t - g * 10;
    int c_ = counts[g];
    float inv = 1.f / (float)(c_ > 1 ? c_ : 1);
    float acc = bc[o];
    for (int c = 0; c < 64; ++c)
        acc += sums[g * 64 + c] * inv * Wc[c * 10 + o];
    out[t] = acc;
}

// ---------------------------------------------------------------------------
extern "C" void kernel_launch(void* const* d_in, const int* in_sizes, int n_in,
                              void* d_out, int out_size, void* d_ws, size_t ws_size,
                              hipStream_t stream) {
    const float* x   = (const float*)d_in[0];
    const int*   ei  = (const int*)d_in[1];
    const int*   bat = (const int*)d_in[2];
    const float* W1  = (const float*)d_in[3];
    const float* as1 = (const float*)d_in[4];
    const float* ad1 = (const float*)d_in[5];
    const float* b1  = (const float*)d_in[6];
    const float* W2  = (const float*)d_in[7];
    const float* as2 = (const float*)d_in[8];
    const float* ad2 = (const float*)d_in[9];
    const float* b2  = (const float*)d_in[10];
    const float* W3  = (const float*)d_in[11];
    const float* as3 = (const float*)d_in[12];
    const float* ad3 = (const float*)d_in[13];
    const float* b3  = (const float*)d_in[14];
    const float* Wc  = (const float*)d_in[15];
    const float* bc  = (const float*)d_in[16];
    float* out = (float*)d_out;

    const int N = in_sizes[2];          // 50000 nodes
    const int E = in_sizes[1] / 2;      // 800000 edges
    const int M = E + N;                // + self loops
    const int IN_C = in_sizes[0] / N;   // 128
    const int G = out_size / 10;        // 64 graphs

    // -------- workspace carve (256B aligned) --------
    char* p = (char*)d_ws;
    auto carve = [&](size_t bytes) -> void* {
        void* r = (void*)p;
        p += (bytes + 255) & ~(size_t)255;
        return r;
    };
    float* hA   = (float*)carve((size_t)N * 256 * 4);
    float* hB   = (float*)carve((size_t)N * 256 * 4);
    float* asrc = (float*)carve((size_t)N * 4 * 4);
    float* adst = (float*)carve((size_t)N * 4 * 4);
    float* sums = (float*)carve((size_t)G * 64 * 4);
    int*   cnts = (int*)carve((size_t)G * 4);
    int*   deg  = (int*)carve((size_t)N * 4);      // reused as scatter cursor
    int*   iptr = (int*)carve((size_t)(N + 1) * 4);
    int*   csr  = (int*)carve((size_t)M * 4);
    (void)ws_size; (void)n_in;

    // -------- CSR build (shared by all 3 layers) --------
    hipMemsetAsync(deg, 0, (size_t)N * 4, stream);
    count_kernel<<<(M + 255) / 256, 256, 0, stream>>>(ei, deg, E, N);
    scan_kernel<<<1, 1024, 0, stream>>>(deg, iptr, N);
    hipMemcpyAsync(deg, iptr, (size_t)N * 4, hipMemcpyDeviceToDevice, stream);
    scatter_kernel<<<(M + 255) / 256, 256, 0, stream>>>(ei, deg, csr, E, N);

    // -------- layer 1: x[N,128] -> hB[N,256] --------
    {
        dim3 grid((N + 127) / 128, 4);
        gemm_alpha_kernel<<<grid, 256, 0, stream>>>(x, W1, hA, as1, ad1, asrc, adst, N, IN_C, 256, 4);
    }
    aggregate4_kernel<<<(N + 3) / 4, 256, 0, stream>>>(hA, asrc, adst, iptr, csr, b1, hB, N, 1);

    // -------- layer 2: hB[N,256] -> hB[N,256] --------
    {
        dim3 grid((N + 127) / 128, 4);
        gemm_alpha_kernel<<<grid, 256, 0, stream>>>(hB, W2, hA, as2, ad2, asrc, adst, N, 256, 256, 4);
    }
    aggregate4_kernel<<<(N + 3) / 4, 256, 0, stream>>>(hA, asrc, adst, iptr, csr, b2, hB, N, 1);

    // -------- layer 3: hB[N,256] -> hB[N,64] (1 head, no ELU) --------
    {
        dim3 grid((N + 127) / 128, 1);
        gemm_alpha_kernel<<<grid, 256, 0, stream>>>(hB, W3, hA, as3, ad3, asrc, adst, N, 256, 64, 1);
    }
    aggregate_kernel<<<(N + 3) / 4, 256, 0, stream>>>(hA, asrc, adst, iptr, csr, b3, hB, N, 1, 0);

    // -------- pool + classify --------
    hipMemsetAsync(sums, 0, (size_t)G * 64 * 4, stream);
    hipMemsetAsync(cnts, 0, (size_t)G * 4, stream);
    pool_kernel<<<(N + POOL_CHUNK - 1) / POOL_CHUNK, 64, 0, stream>>>(hB, bat, sums, cnts, N);
    classify_kernel<<<1, 640, 0, stream>>>(sums, cnts, Wc, bc, out, G);
}

// Round 5
// 733.442 us; speedup vs baseline: 1.3500x; 1.0621x over previous
//
#include <hip/hip_runtime.h>

#define NEG_SLOPE 0.2f
#define EPSV 1e-16f

// ---------------------------------------------------------------------------
// CSR build (by destination node), self-loops appended after the E real edges
// ---------------------------------------------------------------------------
__global__ __launch_bounds__(256)
void count_kernel(const int* __restrict__ ei, int* __restrict__ deg, int E, int n) {
    int i = blockIdx.x * blockDim.x + threadIdx.x;
    int M = E + n;
    if (i >= M) return;
    int d = (i < E) ? ei[E + i] : (i - E);
    atomicAdd(&deg[d], 1);
}

// scan1: per-block (1024) inclusive scan; partials to indptr[i+1], totals to bsum
__global__ __launch_bounds__(1024)
void scan1_kernel(const int* __restrict__ deg, int* __restrict__ indptr,
                  int* __restrict__ bsum, int n) {
    __shared__ int wsum[16];
    const int t = threadIdx.x;
    const int lane = t & 63;
    const int w = t >> 6;
    const int i = blockIdx.x * 1024 + t;
    int v = (i < n) ? deg[i] : 0;
    int s = v;
    #pragma unroll
    for (int off = 1; off < 64; off <<= 1) {
        int u = __shfl_up(s, off);
        if (lane >= off) s += u;
    }
    if (lane == 63) wsum[w] = s;
    __syncthreads();
    if (t < 16) {
        int ws_ = wsum[t];
        #pragma unroll
        for (int off = 1; off < 16; off <<= 1) {
            int u = __shfl_up(ws_, off);
            if (t >= off) ws_ += u;
        }
        wsum[t] = ws_;
    }
    __syncthreads();
    int woff = (w > 0) ? wsum[w - 1] : 0;
    if (i < n) indptr[i + 1] = woff + s;
    if (t == 0) bsum[blockIdx.x] = wsum[15];
}

// scan2: exclusive scan of <=64 block sums (one wave)
__global__ __launch_bounds__(64)
void scan2_kernel(int* __restrict__ bsum, int nb) {
    int t = threadIdx.x;
    int v = (t < nb) ? bsum[t] : 0;
    int s = v;
    #pragma unroll
    for (int off = 1; off < 64; off <<= 1) {
        int u = __shfl_up(s, off);
        if (t >= off) s += u;
    }
    if (t < nb) bsum[t] = s - v;
}

// scan3: add block offsets, finalize indptr[0]
__global__ __launch_bounds__(1024)
void scan3_kernel(int* __restrict__ indptr, const int* __restrict__ bsum, int n) {
    int i = blockIdx.x * 1024 + threadIdx.x;
    if (i < n) indptr[i + 1] += bsum[blockIdx.x];
    if (i == 0) indptr[0] = 0;
}

__global__ __launch_bounds__(256)
void scatter_kernel(const int* __restrict__ ei, int* __restrict__ cursor,
                    int* __restrict__ csr_src, int E, int n) {
    int i = blockIdx.x * blockDim.x + threadIdx.x;
    int M = E + n;
    if (i >= M) return;
    int s, d;
    if (i < E) { s = ei[i]; d = ei[E + i]; }
    else       { s = i - E; d = i - E; }
    int pos = atomicAdd(&cursor[d], 1);
    csr_src[pos] = s;
}

// ---------------------------------------------------------------------------
// fp32 GEMM (128x64 tile, 256 threads, 8x4 acc) with FUSED alpha epilogue.
// ---------------------------------------------------------------------------
__global__ __launch_bounds__(256)
void gemm_alpha_kernel(const float* __restrict__ A, const float* __restrict__ B,
                       float* __restrict__ C,
                       const float* __restrict__ a_src, const float* __restrict__ a_dst,
                       float* __restrict__ asrc, float* __restrict__ adst,
                       int M, int K, int N, int H) {
    constexpr int TBM = 128, TBN = 64, TBK = 16;
    __shared__ float As[TBK][TBM + 4];
    __shared__ float Bs[TBK][TBN + 4];
    const int tid = threadIdx.x;
    const int tr = tid >> 4;
    const int tc = tid & 15;
    const int row0 = blockIdx.x * TBM;
    const int col0 = blockIdx.y * TBN;
    float acc[8][4] = {};
    for (int k0 = 0; k0 < K; k0 += TBK) {
        #pragma unroll
        for (int it = 0; it < 2; ++it) {
            int idx = tid + it * 256;
            int r = idx >> 2;
            int q = idx & 3;
            int gr = row0 + r;
            float4 v = make_float4(0.f, 0.f, 0.f, 0.f);
            if (gr < M)
                v = *reinterpret_cast<const float4*>(A + (long)gr * K + k0 + 4 * q);
            As[4 * q + 0][r] = v.x;
            As[4 * q + 1][r] = v.y;
            As[4 * q + 2][r] = v.z;
            As[4 * q + 3][r] = v.w;
        }
        {
            int kk = tid >> 4;
            int c4 = tid & 15;
            float4 v = *reinterpret_cast<const float4*>(B + (long)(k0 + kk) * N + col0 + 4 * c4);
            *reinterpret_cast<float4*>(&Bs[kk][4 * c4]) = v;
        }
        __syncthreads();
        #pragma unroll
        for (int kk = 0; kk < TBK; ++kk) {
            float4 a0 = *reinterpret_cast<const float4*>(&As[kk][tr * 8]);
            float4 a1 = *reinterpret_cast<const float4*>(&As[kk][tr * 8 + 4]);
            float4 b0 = *reinterpret_cast<const float4*>(&Bs[kk][tc * 4]);
            float av[8] = {a0.x, a0.y, a0.z, a0.w, a1.x, a1.y, a1.z, a1.w};
            #pragma unroll
            for (int i = 0; i < 8; ++i) {
                acc[i][0] += av[i] * b0.x;
                acc[i][1] += av[i] * b0.y;
                acc[i][2] += av[i] * b0.z;
                acc[i][3] += av[i] * b0.w;
            }
        }
        __syncthreads();
    }
    #pragma unroll
    for (int i = 0; i < 8; ++i) {
        int gr = row0 + tr * 8 + i;
        if (gr < M) {
            float4 v = make_float4(acc[i][0], acc[i][1], acc[i][2], acc[i][3]);
            *reinterpret_cast<float4*>(&C[(long)gr * N + col0 + tc * 4]) = v;
        }
    }
    const int hd = col0 >> 6;
    float4 awS = *reinterpret_cast<const float4*>(a_src + col0 + tc * 4);
    float4 awD = *reinterpret_cast<const float4*>(a_dst + col0 + tc * 4);
    #pragma unroll
    for (int i = 0; i < 8; ++i) {
        float s = acc[i][0] * awS.x + acc[i][1] * awS.y + acc[i][2] * awS.z + acc[i][3] * awS.w;
        float d = acc[i][0] * awD.x + acc[i][1] * awD.y + acc[i][2] * awD.z + acc[i][3] * awD.w;
        #pragma unroll
        for (int off = 1; off < 16; off <<= 1) {
            s += __shfl_xor(s, off);
            d += __shfl_xor(d, off);
        }
        int gr = row0 + tr * 8 + i;
        if (tc == 0 && gr < M) {
            asrc[gr * H + hd] = s;
            adst[gr * H + hd] = d;
        }
    }
}

// ---------------------------------------------------------------------------
// Aggregate, H=4: ONE wave per node, chunk=64 (4 e-slots/lane), pass B x8 MLP.
// ---------------------------------------------------------------------------
__global__ __launch_bounds__(256)
void aggregate4_kernel(const float* __restrict__ h, const float* __restrict__ asrc,
                       const float* __restrict__ adst, const int* __restrict__ indptr,
                       const int* __restrict__ csr_src, const float* __restrict__ bias,
                       float* __restrict__ out, int n, int apply_elu) {
    __shared__ int   sOff[4][64];
    __shared__ float sEx[4][4][64];     // [wave][head][edge-slot]
    const int node = (blockIdx.x * blockDim.x + threadIdx.x) >> 6;
    const int lane = threadIdx.x & 63;
    const int w    = threadIdx.x >> 6;
    if (node >= n) return;
    const int hd   = lane >> 4;
    const int eidx = lane & 15;
    const int beg = indptr[node], end = indptr[node + 1];
    const float ad = adst[node * 4 + hd];
    const float* __restrict__ hrow = h + 4 * lane;   // + s*256 per edge

    float m = -3.4e38f, sum_ex = 0.f;
    float ax = 0.f, ay = 0.f, az = 0.f, aw = 0.f;
    for (int cb = beg; cb < end; cb += 64) {
        const int cnt = min(64, end - cb);
        // ---- pass A: 4 edge-slots per lane, independent gathers ----
        int s[4];
        float e[4];
        #pragma unroll
        for (int j = 0; j < 4; ++j) {
            int idx = eidx + 16 * j;
            s[j] = (idx < cnt) ? csr_src[cb + idx] : 0;
        }
        #pragma unroll
        for (int j = 0; j < 4; ++j) {
            float t = asrc[s[j] * 4 + hd] + ad;
            t = t > 0.f ? t : NEG_SLOPE * t;
            e[j] = (eidx + 16 * j < cnt) ? t : -3.4e38f;
        }
        float cm = fmaxf(fmaxf(e[0], e[1]), fmaxf(e[2], e[3]));
        #pragma unroll
        for (int off = 1; off < 16; off <<= 1) cm = fmaxf(cm, __shfl_xor(cm, off));
        const float nm = fmaxf(m, cm);
        const float scale = __expf(m - nm);      // 0 on first chunk
        float ex[4];
        #pragma unroll
        for (int j = 0; j < 4; ++j)
            ex[j] = (eidx + 16 * j < cnt) ? __expf(e[j] - nm) : 0.f;
        float csum = (ex[0] + ex[1]) + (ex[2] + ex[3]);
        #pragma unroll
        for (int off = 1; off < 16; off <<= 1) csum += __shfl_xor(csum, off);
        sum_ex = sum_ex * scale + csum;
        ax *= scale; ay *= scale; az *= scale; aw *= scale;
        m = nm;
        #pragma unroll
        for (int j = 0; j < 4; ++j) sEx[w][hd][eidx + 16 * j] = ex[j];
        if (hd == 0) {
            #pragma unroll
            for (int j = 0; j < 4; ++j) sOff[w][eidx + 16 * j] = s[j] << 8;
        }
        // wave-private LDS slice: compiler inserts lgkmcnt before reads
        // ---- pass B: gather full rows, 8 loads in flight ----
        int i = 0;
        for (; i + 8 <= cnt; i += 8) {
            int o[8];
            float ee[8];
            float4 v[8];
            #pragma unroll
            for (int u = 0; u < 8; ++u) o[u] = sOff[w][i + u];
            #pragma unroll
            for (int u = 0; u < 8; ++u) v[u] = *reinterpret_cast<const float4*>(hrow + o[u]);
            #pragma unroll
            for (int u = 0; u < 8; ++u) ee[u] = sEx[w][hd][i + u];
            #pragma unroll
            for (int u = 0; u < 8; ++u) {
                ax += ee[u] * v[u].x;
                ay += ee[u] * v[u].y;
                az += ee[u] * v[u].z;
                aw += ee[u] * v[u].w;
            }
        }
        for (; i < cnt; ++i) {
            int o = sOff[w][i];
            float ee = sEx[w][hd][i];
            float4 v = *reinterpret_cast<const float4*>(hrow + o);
            ax += ee * v.x; ay += ee * v.y; az += ee * v.z; aw += ee * v.w;
        }
    }
    const float inv = 1.f / (sum_ex + EPSV);
    float4 b4 = *reinterpret_cast<const float4*>(bias + 4 * lane);
    float ox = ax * inv + b4.x;
    float oy = ay * inv + b4.y;
    float oz = az * inv + b4.z;
    float ow = aw * inv + b4.w;
    if (apply_elu) {
        ox = ox > 0.f ? ox : expm1f(ox);
        oy = oy > 0.f ? oy : expm1f(oy);
        oz = oz > 0.f ? oz : expm1f(oz);
        ow = ow > 0.f ? ow : expm1f(ow);
    }
    float4 o4 = make_float4(ox, oy, oz, ow);
    *reinterpret_cast<float4*>(out + (long)node * 256 + 4 * lane) = o4;
}

// ---------------------------------------------------------------------------
// Aggregate, H=1. Wave = 64 lanes = channels; pass B unrolled x8.
// ---------------------------------------------------------------------------
__global__ __launch_bounds__(256)
void aggregate_kernel(const float* __restrict__ h, const float* __restrict__ asrc,
                      const float* __restrict__ adst, const int* __restrict__ indptr,
                      const int* __restrict__ csr_src, const float* __restrict__ bias,
                      float* __restrict__ out, int n, int H, int apply_elu) {
    __shared__ int   sInd[4][64];
    __shared__ float sEx[4][64];
    const int wid  = (blockIdx.x * blockDim.x + threadIdx.x) >> 6;
    const int lane = threadIdx.x & 63;
    const int w    = threadIdx.x >> 6;
    const int node = wid / H;
    const int hd   = wid - node * H;
    if (node >= n) return;
    const int HC = H * 64;
    const int beg = indptr[node];
    const int end = indptr[node + 1];
    const float ad = adst[node * H + hd];
    const float* __restrict__ hh = h + hd * 64 + lane;

    float m = -3.4e38f, sum_ex = 0.f, acc = 0.f;
    for (int cb = beg; cb < end; cb += 64) {
        const int cnt = min(64, end - cb);
        int s = 0;
        float e = -3.4e38f;
        if (lane < cnt) {
            s = csr_src[cb + lane];
            e = asrc[s * H + hd] + ad;
            e = e > 0.f ? e : NEG_SLOPE * e;
        }
        float cm = e;
        #pragma unroll
        for (int off = 32; off > 0; off >>= 1) cm = fmaxf(cm, __shfl_xor(cm, off));
        const float nm = fmaxf(m, cm);
        const float scale = __expf(m - nm);
        const float ex = (lane < cnt) ? __expf(e - nm) : 0.f;
        float cs = ex;
        #pragma unroll
        for (int off = 32; off > 0; off >>= 1) cs += __shfl_xor(cs, off);
        sum_ex = sum_ex * scale + cs;
        acc *= scale;
        m = nm;
        sInd[w][lane] = s;
        sEx[w][lane]  = ex;
        int i = 0;
        for (; i + 8 <= cnt; i += 8) {
            int si[8];
            float ei_[8], vi[8];
            #pragma unroll
            for (int u = 0; u < 8; ++u) si[u] = sInd[w][i + u];
            #pragma unroll
            for (int u = 0; u < 8; ++u) vi[u] = hh[(long)si[u] * HC];
            #pragma unroll
            for (int u = 0; u < 8; ++u) ei_[u] = sEx[w][i + u];
            #pragma unroll
            for (int u = 0; u < 8; ++u) acc += ei_[u] * vi[u];
        }
        for (; i < cnt; ++i)
            acc += sEx[w][i] * hh[(long)sInd[w][i] * HC];
    }
    float o = acc / (sum_ex + EPSV) + bias[hd * 64 + lane];
    if (apply_elu) o = o > 0.f ? o : expm1f(o);
    out[(long)node * HC + hd * 64 + lane] = o;
}

// ---------------------------------------------------------------------------
// Global mean pool (batch is sorted) + classifier
// ---------------------------------------------------------------------------
constexpr int POOL_CHUNK = 128;

__global__ __launch_bounds__(64)
void pool_kernel(const float* __restrict__ h, const int* __restrict__ batch,
                 float* __restrict__ sums, int* __restrict__ counts, int n) {
    int lane = threadIdx.x;
    int start = blockIdx.x * POOL_CHUNK;
    if (start >= n) return;
    int end = min(start + POOL_CHUNK, n);
    int gcur = batch[start];
    float acc = 0.f;
    int run = 0;
    for (int i = start; i < end; ++i) {
        int g = batch[i];
        if (g != gcur) {
            atomicAdd(&sums[gcur * 64 + lane], acc);
            if (lane == 0) atomicAdd(&counts[gcur], run);
            acc = 0.f; run = 0; gcur = g;
        }
        acc += h[(long)i * 64 + lane];
        ++run;
    }
    atomicAdd(&sums[gcur * 64 + lane], acc);
    if (lane == 0) atomicAdd(&counts[gcur], run);
}

__global__ void classify_kernel(const float* __restrict__ sums, const int* __restrict__ counts,
                                const float* __restrict__ Wc, const float* __restrict__ bc,
                                float* __restrict__ out, int G) {
    int t = threadIdx.x;
    if (t >= G * 10) return;
    int g = t / 10, o = t - g * 10;
    int c_ = counts[g];
    float inv = 1.f / (float)(c_ > 1 ? c_ : 1);
    float acc = bc[o];
    for (int c = 0; c < 64; ++c)
        acc += sums[g * 64 + c] * inv * Wc[c * 10 + o];
    out[t] = acc;
}

// ---------------------------------------------------------------------------
extern "C" void kernel_launch(void* const* d_in, const int* in_sizes, int n_in,
                              void* d_out, int out_size, void* d_ws, size_t ws_size,
                              hipStream_t stream) {
    const float* x   = (const float*)d_in[0];
    const int*   ei  = (const int*)d_in[1];
    const int*   bat = (const int*)d_in[2];
    const float* W1  = (const float*)d_in[3];
    const float* as1 = (const float*)d_in[4];
    const float* ad1 = (const float*)d_in[5];
    const float* b1  = (const float*)d_in[6];
    const float* W2  = (const float*)d_in[7];
    const float* as2 = (const float*)d_in[8];
    const float* ad2 = (const float*)d_in[9];
    const float* b2  = (const float*)d_in[10];
    const float* W3  = (const float*)d_in[11];
    const float* as3 = (const float*)d_in[12];
    const float* ad3 = (const float*)d_in[13];
    const float* b3  = (const float*)d_in[14];
    const float* Wc  = (const float*)d_in[15];
    const float* bc  = (const float*)d_in[16];
    float* out = (float*)d_out;

    const int N = in_sizes[2];          // 50000 nodes
    const int E = in_sizes[1] / 2;      // 800000 edges
    const int M = E + N;                // + self loops
    const int IN_C = in_sizes[0] / N;   // 128
    const int G = out_size / 10;        // 64 graphs

    // -------- workspace carve (256B aligned) --------
    char* p = (char*)d_ws;
    auto carve = [&](size_t bytes) -> void* {
        void* r = (void*)p;
        p += (bytes + 255) & ~(size_t)255;
        return r;
    };
    float* hA   = (float*)carve((size_t)N * 256 * 4);
    float* hB   = (float*)carve((size_t)N * 256 * 4);
    float* asrc = (float*)carve((size_t)N * 4 * 4);
    float* adst = (float*)carve((size_t)N * 4 * 4);
    float* sums = (float*)carve((size_t)G * 64 * 4);
    int*   cnts = (int*)carve((size_t)G * 4);
    int*   deg  = (int*)carve((size_t)N * 4);      // reused as scatter cursor
    int*   iptr = (int*)carve((size_t)(N + 1) * 4);
    int*   csr  = (int*)carve((size_t)M * 4);
    int*   bsum = (int*)carve(256 * 4);
    (void)ws_size; (void)n_in;

    const int NB = (N + 1023) / 1024;   // 49 blocks (<= 64)

    // -------- CSR build (shared by all 3 layers) --------
    hipMemsetAsync(deg, 0, (size_t)N * 4, stream);
    count_kernel<<<(M + 255) / 256, 256, 0, stream>>>(ei, deg, E, N);
    scan1_kernel<<<NB, 1024, 0, stream>>>(deg, iptr, bsum, N);
    scan2_kernel<<<1, 64, 0, stream>>>(bsum, NB);
    scan3_kernel<<<NB, 1024, 0, stream>>>(iptr, bsum, N);
    hipMemcpyAsync(deg, iptr, (size_t)N * 4, hipMemcpyDeviceToDevice, stream);
    scatter_kernel<<<(M + 255) / 256, 256, 0, stream>>>(ei, deg, csr, E, N);

    // -------- layer 1: x[N,128] -> hB[N,256] --------
    {
        dim3 grid((N + 127) / 128, 4);
        gemm_alpha_kernel<<<grid, 256, 0, stream>>>(x, W1, hA, as1, ad1, asrc, adst, N, IN_C, 256, 4);
    }
    aggregate4_kernel<<<(N + 3) / 4, 256, 0, stream>>>(hA, asrc, adst, iptr, csr, b1, hB, N, 1);

    // -------- layer 2: hB[N,256] -> hB[N,256] --------
    {
        dim3 grid((N + 127) / 128, 4);
        gemm_alpha_kernel<<<grid, 256, 0, stream>>>(hB, W2, hA, as2, ad2, asrc, adst, N, 256, 256, 4);
    }
    aggregate4_kernel<<<(N + 3) / 4, 256, 0, stream>>>(hA, asrc, adst, iptr, csr, b2, hB, N, 1);

    // -------- layer 3: hB[N,256] -> hB[N,64] (1 head, no ELU) --------
    {
        dim3 grid((N + 127) / 128, 1);
        gemm_alpha_kernel<<<grid, 256, 0, stream>>>(hB, W3, hA, as3, ad3, asrc, adst, N, 256, 64, 1);
    }
    aggregate_kernel<<<(N + 3) / 4, 256, 0, stream>>>(hA, asrc, adst, iptr, csr, b3, hB, N, 1, 0);

    // -------- pool + classify --------
    hipMemsetAsync(sums, 0, (size_t)G * 64 * 4, stream);
    hipMemsetAsync(cnts, 0, (size_t)G * 4, stream);
    pool_kernel<<<(N + POOL_CHUNK - 1) / POOL_CHUNK, 64, 0, stream>>>(hB, bat, sums, cnts, N);
    classify_kernel<<<1, 640, 0, stream>>>(sums, cnts, Wc, bc, out, G);
}

// Round 6
// 610.451 us; speedup vs baseline: 1.6220x; 1.2015x over previous
//
#include <hip/hip_runtime.h>

#define NEG_SLOPE 0.2f
#define EPSV 1e-16f

typedef unsigned short ushort_t;

__device__ __forceinline__ ushort_t f2bf(float f) {
    union { float f; unsigned u; } v; v.f = f;
    unsigned r = v.u + 0x7FFFu + ((v.u >> 16) & 1u);   // round-nearest-even
    return (ushort_t)(r >> 16);
}
__device__ __forceinline__ float bf2f(ushort_t u) {
    union { unsigned u; float f; } v; v.u = ((unsigned)u) << 16;
    return v.f;
}

// ---------------------------------------------------------------------------
// CSR build (by destination node), self-loops appended after the E real edges
// ---------------------------------------------------------------------------
__global__ __launch_bounds__(256)
void count_kernel(const int* __restrict__ ei, int* __restrict__ deg, int E, int n) {
    int i = blockIdx.x * blockDim.x + threadIdx.x;
    int M = E + n;
    if (i >= M) return;
    int d = (i < E) ? ei[E + i] : (i - E);
    atomicAdd(&deg[d], 1);
}

__global__ __launch_bounds__(1024)
void scan1_kernel(const int* __restrict__ deg, int* __restrict__ indptr,
                  int* __restrict__ bsum, int n) {
    __shared__ int wsum[16];
    const int t = threadIdx.x;
    const int lane = t & 63;
    const int w = t >> 6;
    const int i = blockIdx.x * 1024 + t;
    int v = (i < n) ? deg[i] : 0;
    int s = v;
    #pragma unroll
    for (int off = 1; off < 64; off <<= 1) {
        int u = __shfl_up(s, off);
        if (lane >= off) s += u;
    }
    if (lane == 63) wsum[w] = s;
    __syncthreads();
    if (t < 16) {
        int ws_ = wsum[t];
        #pragma unroll
        for (int off = 1; off < 16; off <<= 1) {
            int u = __shfl_up(ws_, off);
            if (t >= off) ws_ += u;
        }
        wsum[t] = ws_;
    }
    __syncthreads();
    int woff = (w > 0) ? wsum[w - 1] : 0;
    if (i < n) indptr[i + 1] = woff + s;
    if (t == 0) bsum[blockIdx.x] = wsum[15];
}

__global__ __launch_bounds__(64)
void scan2_kernel(int* __restrict__ bsum, int nb) {
    int t = threadIdx.x;
    int v = (t < nb) ? bsum[t] : 0;
    int s = v;
    #pragma unroll
    for (int off = 1; off < 64; off <<= 1) {
        int u = __shfl_up(s, off);
        if (t >= off) s += u;
    }
    if (t < nb) bsum[t] = s - v;
}

__global__ __launch_bounds__(1024)
void scan3_kernel(int* __restrict__ indptr, const int* __restrict__ bsum, int n) {
    int i = blockIdx.x * 1024 + threadIdx.x;
    if (i < n) indptr[i + 1] += bsum[blockIdx.x];
    if (i == 0) indptr[0] = 0;
}

__global__ __launch_bounds__(256)
void scatter_kernel(const int* __restrict__ ei, int* __restrict__ cursor,
                    int* __restrict__ csr_src, int E, int n) {
    int i = blockIdx.x * blockDim.x + threadIdx.x;
    int M = E + n;
    if (i >= M) return;
    int s, d;
    if (i < E) { s = ei[i]; d = ei[E + i]; }
    else       { s = i - E; d = i - E; }
    int pos = atomicAdd(&cursor[d], 1);
    csr_src[pos] = s;
}

// ---------------------------------------------------------------------------
// fp32 GEMM (128x64 tile, 256 threads, 8x4 acc), bf16 C-store, FUSED alpha
// epilogue (alpha computed from fp32 accumulators).
// ---------------------------------------------------------------------------
__global__ __launch_bounds__(256)
void gemm_alpha_kernel(const float* __restrict__ A, const float* __restrict__ B,
                       ushort_t* __restrict__ C,
                       const float* __restrict__ a_src, const float* __restrict__ a_dst,
                       float* __restrict__ asrc, float* __restrict__ adst,
                       int M, int K, int N, int H) {
    constexpr int TBM = 128, TBN = 64, TBK = 16;
    __shared__ float As[TBK][TBM + 4];
    __shared__ float Bs[TBK][TBN + 4];
    const int tid = threadIdx.x;
    const int tr = tid >> 4;
    const int tc = tid & 15;
    const int row0 = blockIdx.x * TBM;
    const int col0 = blockIdx.y * TBN;
    float acc[8][4] = {};
    for (int k0 = 0; k0 < K; k0 += TBK) {
        #pragma unroll
        for (int it = 0; it < 2; ++it) {
            int idx = tid + it * 256;
            int r = idx >> 2;
            int q = idx & 3;
            int gr = row0 + r;
            float4 v = make_float4(0.f, 0.f, 0.f, 0.f);
            if (gr < M)
                v = *reinterpret_cast<const float4*>(A + (long)gr * K + k0 + 4 * q);
            As[4 * q + 0][r] = v.x;
            As[4 * q + 1][r] = v.y;
            As[4 * q + 2][r] = v.z;
            As[4 * q + 3][r] = v.w;
        }
        {
            int kk = tid >> 4;
            int c4 = tid & 15;
            float4 v = *reinterpret_cast<const float4*>(B + (long)(k0 + kk) * N + col0 + 4 * c4);
            *reinterpret_cast<float4*>(&Bs[kk][4 * c4]) = v;
        }
        __syncthreads();
        #pragma unroll
        for (int kk = 0; kk < TBK; ++kk) {
            float4 a0 = *reinterpret_cast<const float4*>(&As[kk][tr * 8]);
            float4 a1 = *reinterpret_cast<const float4*>(&As[kk][tr * 8 + 4]);
            float4 b0 = *reinterpret_cast<const float4*>(&Bs[kk][tc * 4]);
            float av[8] = {a0.x, a0.y, a0.z, a0.w, a1.x, a1.y, a1.z, a1.w};
            #pragma unroll
            for (int i = 0; i < 8; ++i) {
                acc[i][0] += av[i] * b0.x;
                acc[i][1] += av[i] * b0.y;
                acc[i][2] += av[i] * b0.z;
                acc[i][3] += av[i] * b0.w;
            }
        }
        __syncthreads();
    }
    // ---- bf16 C store (8B per row slice) ----
    #pragma unroll
    for (int i = 0; i < 8; ++i) {
        int gr = row0 + tr * 8 + i;
        if (gr < M) {
            ushort4 v;
            v.x = f2bf(acc[i][0]);
            v.y = f2bf(acc[i][1]);
            v.z = f2bf(acc[i][2]);
            v.w = f2bf(acc[i][3]);
            *reinterpret_cast<ushort4*>(&C[(long)gr * N + col0 + tc * 4]) = v;
        }
    }
    // ---- fused alpha epilogue (head hd = col0/64), fp32-exact ----
    const int hd = col0 >> 6;
    float4 awS = *reinterpret_cast<const float4*>(a_src + col0 + tc * 4);
    float4 awD = *reinterpret_cast<const float4*>(a_dst + col0 + tc * 4);
    #pragma unroll
    for (int i = 0; i < 8; ++i) {
        float s = acc[i][0] * awS.x + acc[i][1] * awS.y + acc[i][2] * awS.z + acc[i][3] * awS.w;
        float d = acc[i][0] * awD.x + acc[i][1] * awD.y + acc[i][2] * awD.z + acc[i][3] * awD.w;
        #pragma unroll
        for (int off = 1; off < 16; off <<= 1) {
            s += __shfl_xor(s, off);
            d += __shfl_xor(d, off);
        }
        int gr = row0 + tr * 8 + i;
        if (tc == 0 && gr < M) {
            asrc[gr * H + hd] = s;
            adst[gr * H + hd] = d;
        }
    }
}

// ---------------------------------------------------------------------------
// Aggregate, H=4: ONE wave per node; gather table h is bf16 [N][256].
// Pass A chunk=64 (4 e-slots/lane); pass B x8 MLP, 512B rows (ushort4/lane).
// ---------------------------------------------------------------------------
__global__ __launch_bounds__(256)
void aggregate4_kernel(const ushort_t* __restrict__ h, const float* __restrict__ asrc,
                       const float* __restrict__ adst, const int* __restrict__ indptr,
                       const int* __restrict__ csr_src, const float* __restrict__ bias,
                       float* __restrict__ out, int n, int apply_elu) {
    __shared__ int   sOff[4][64];
    __shared__ float sEx[4][4][68];     // head stride 68 floats -> bank-spread
    const int node = (blockIdx.x * blockDim.x + threadIdx.x) >> 6;
    const int lane = threadIdx.x & 63;
    const int w    = threadIdx.x >> 6;
    if (node >= n) return;
    const int hd   = lane >> 4;
    const int eidx = lane & 15;
    const int beg = indptr[node], end = indptr[node + 1];
    const float ad = adst[node * 4 + hd];
    const ushort_t* __restrict__ hrow = h + 4 * lane;   // + s*256 per edge

    float m = -3.4e38f, sum_ex = 0.f;
    float ax = 0.f, ay = 0.f, az = 0.f, aw = 0.f;
    for (int cb = beg; cb < end; cb += 64) {
        const int cnt = min(64, end - cb);
        // ---- pass A ----
        int s[4];
        float e[4];
        #pragma unroll
        for (int j = 0; j < 4; ++j) {
            int idx = eidx + 16 * j;
            s[j] = (idx < cnt) ? csr_src[cb + idx] : 0;
        }
        #pragma unroll
        for (int j = 0; j < 4; ++j) {
            float t = asrc[s[j] * 4 + hd] + ad;
            t = t > 0.f ? t : NEG_SLOPE * t;
            e[j] = (eidx + 16 * j < cnt) ? t : -3.4e38f;
        }
        float cm = fmaxf(fmaxf(e[0], e[1]), fmaxf(e[2], e[3]));
        #pragma unroll
        for (int off = 1; off < 16; off <<= 1) cm = fmaxf(cm, __shfl_xor(cm, off));
        const float nm = fmaxf(m, cm);
        const float scale = __expf(m - nm);      // 0 on first chunk
        float ex[4];
        #pragma unroll
        for (int j = 0; j < 4; ++j)
            ex[j] = (eidx + 16 * j < cnt) ? __expf(e[j] - nm) : 0.f;
        float csum = (ex[0] + ex[1]) + (ex[2] + ex[3]);
        #pragma unroll
        for (int off = 1; off < 16; off <<= 1) csum += __shfl_xor(csum, off);
        sum_ex = sum_ex * scale + csum;
        ax *= scale; ay *= scale; az *= scale; aw *= scale;
        m = nm;
        #pragma unroll
        for (int j = 0; j < 4; ++j) sEx[w][hd][eidx + 16 * j] = ex[j];
        if (hd == 0) {
            #pragma unroll
            for (int j = 0; j < 4; ++j) sOff[w][eidx + 16 * j] = s[j] << 8;
        }
        // ---- pass B: gather bf16 rows, 8 loads in flight ----
        int i = 0;
        for (; i + 8 <= cnt; i += 8) {
            int o[8];
            float ee[8];
            ushort4 v[8];
            #pragma unroll
            for (int u = 0; u < 8; ++u) o[u] = sOff[w][i + u];
            #pragma unroll
            for (int u = 0; u < 8; ++u) v[u] = *reinterpret_cast<const ushort4*>(hrow + o[u]);
            #pragma unroll
            for (int u = 0; u < 8; ++u) ee[u] = sEx[w][hd][i + u];
            #pragma unroll
            for (int u = 0; u < 8; ++u) {
                ax += ee[u] * bf2f(v[u].x);
                ay += ee[u] * bf2f(v[u].y);
                az += ee[u] * bf2f(v[u].z);
                aw += ee[u] * bf2f(v[u].w);
            }
        }
        for (; i < cnt; ++i) {
            int o = sOff[w][i];
            float ee = sEx[w][hd][i];
            ushort4 v = *reinterpret_cast<const ushort4*>(hrow + o);
            ax += ee * bf2f(v.x); ay += ee * bf2f(v.y);
            az += ee * bf2f(v.z); aw += ee * bf2f(v.w);
        }
    }
    const float inv = 1.f / (sum_ex + EPSV);
    float4 b4 = *reinterpret_cast<const float4*>(bias + 4 * lane);
    float ox = ax * inv + b4.x;
    float oy = ay * inv + b4.y;
    float oz = az * inv + b4.z;
    float ow = aw * inv + b4.w;
    if (apply_elu) {
        ox = ox > 0.f ? ox : expm1f(ox);
        oy = oy > 0.f ? oy : expm1f(oy);
        oz = oz > 0.f ? oz : expm1f(oz);
        ow = ow > 0.f ? ow : expm1f(ow);
    }
    float4 o4 = make_float4(ox, oy, oz, ow);
    *reinterpret_cast<float4*>(out + (long)node * 256 + 4 * lane) = o4;
}

// ---------------------------------------------------------------------------
// Aggregate, H=1: wave = 64 lanes = channels; h is bf16 [N][64].
// ---------------------------------------------------------------------------
__global__ __launch_bounds__(256)
void aggregate_kernel(const ushort_t* __restrict__ h, const float* __restrict__ asrc,
                      const float* __restrict__ adst, const int* __restrict__ indptr,
                      const int* __restrict__ csr_src, const float* __restrict__ bias,
                      float* __restrict__ out, int n, int apply_elu) {
    __shared__ int   sInd[4][64];
    __shared__ float sEx[4][64];
    const int node = (blockIdx.x * blockDim.x + threadIdx.x) >> 6;
    const int lane = threadIdx.x & 63;
    const int w    = threadIdx.x >> 6;
    if (node >= n) return;
    const int beg = indptr[node];
    const int end = indptr[node + 1];
    const float ad = adst[node];
    const ushort_t* __restrict__ hh = h + lane;

    float m = -3.4e38f, sum_ex = 0.f, acc = 0.f;
    for (int cb = beg; cb < end; cb += 64) {
        const int cnt = min(64, end - cb);
        int s = 0;
        float e = -3.4e38f;
        if (lane < cnt) {
            s = csr_src[cb + lane];
            e = asrc[s] + ad;
            e = e > 0.f ? e : NEG_SLOPE * e;
        }
        float cm = e;
        #pragma unroll
        for (int off = 32; off > 0; off >>= 1) cm = fmaxf(cm, __shfl_xor(cm, off));
        const float nm = fmaxf(m, cm);
        const float scale = __expf(m - nm);
        const float ex = (lane < cnt) ? __expf(e - nm) : 0.f;
        float cs = ex;
        #pragma unroll
        for (int off = 32; off > 0; off >>= 1) cs += __shfl_xor(cs, off);
        sum_ex = sum_ex * scale + cs;
        acc *= scale;
        m = nm;
        sInd[w][lane] = s;
        sEx[w][lane]  = ex;
        int i = 0;
        for (; i + 8 <= cnt; i += 8) {
            int si[8];
            float ei_[8], vi[8];
            #pragma unroll
            for (int u = 0; u < 8; ++u) si[u] = sInd[w][i + u];
            #pragma unroll
            for (int u = 0; u < 8; ++u) vi[u] = bf2f(hh[(long)si[u] * 64]);
            #pragma unroll
            for (int u = 0; u < 8; ++u) ei_[u] = sEx[w][i + u];
            #pragma unroll
            for (int u = 0; u < 8; ++u) acc += ei_[u] * vi[u];
        }
        for (; i < cnt; ++i)
            acc += sEx[w][i] * bf2f(hh[(long)sInd[w][i] * 64]);
    }
    float o = acc / (sum_ex + EPSV) + bias[lane];
    if (apply_elu) o = o > 0.f ? o : expm1f(o);
    out[(long)node * 64 + lane] = o;
}

// ---------------------------------------------------------------------------
// Global mean pool (batch is sorted) + classifier
// ---------------------------------------------------------------------------
constexpr int POOL_CHUNK = 128;

__global__ __launch_bounds__(64)
void pool_kernel(const float* __restrict__ h, const int* __restrict__ batch,
                 float* __restrict__ sums, int* __restrict__ counts, int n) {
    int lane = threadIdx.x;
    int start = blockIdx.x * POOL_CHUNK;
    if (start >= n) return;
    int end = min(start + POOL_CHUNK, n);
    int gcur = batch[start];
    float acc = 0.f;
    int run = 0;
    for (int i = start; i < end; ++i) {
        int g = batch[i];
        if (g != gcur) {
            atomicAdd(&sums[gcur * 64 + lane], acc);
            if (lane == 0) atomicAdd(&counts[gcur], run);
            acc = 0.f; run = 0; gcur = g;
        }
        acc += h[(long)i * 64 + lane];
        ++run;
    }
    atomicAdd(&sums[gcur * 64 + lane], acc);
    if (lane == 0) atomicAdd(&counts[gcur], run);
}

__global__ void classify_kernel(const float* __restrict__ sums, const int* __restrict__ counts,
                                const float* __restrict__ Wc, const float* __restrict__ bc,
                                float* __restrict__ out, int G) {
    int t = threadIdx.x;
    if (t >= G * 10) return;
    int g = t / 10, o = t - g * 10;
    int c_ = counts[g];
    float inv = 1.f / (float)(c_ > 1 ? c_ : 1);
    float acc = bc[o];
    for (int c = 0; c < 64; ++c)
        acc += sums[g * 64 + c] * inv * Wc[c * 10 + o];
    out[t] = acc;
}

// ---------------------------------------------------------------------------
extern "C" void kernel_launch(void* const* d_in, const int* in_sizes, int n_in,
                              void* d_out, int out_size, void* d_ws, size_t ws_size,
                              hipStream_t stream) {
    const float* x   = (const float*)d_in[0];
    const int*   ei  = (const int*)d_in[1];
    const int*   bat = (const int*)d_in[2];
    const float* W1  = (const float*)d_in[3];
    const float* as1 = (const float*)d_in[4];
    const float* ad1 = (const float*)d_in[5];
    const float* b1  = (const float*)d_in[6];
    const float* W2  = (const float*)d_in[7];
    const float* as2 = (const float*)d_in[8];
    const float* ad2 = (const float*)d_in[9];
    const float* b2  = (const float*)d_in[10];
    const float* W3  = (const float*)d_in[11];
    const float* as3 = (const float*)d_in[12];
    const float* ad3 = (const float*)d_in[13];
    const float* b3  = (const float*)d_in[14];
    const float* Wc  = (const float*)d_in[15];
    const float* bc  = (const float*)d_in[16];
    float* out = (float*)d_out;

    const int N = in_sizes[2];          // 50000 nodes
    const int E = in_sizes[1] / 2;      // 800000 edges
    const int M = E + N;                // + self loops
    const int IN_C = in_sizes[0] / N;   // 128
    const int G = out_size / 10;        // 64 graphs

    // -------- workspace carve (256B aligned) --------
    char* p = (char*)d_ws;
    auto carve = [&](size_t bytes) -> void* {
        void* r = (void*)p;
        p += (bytes + 255) & ~(size_t)255;
        return r;
    };
    ushort_t* hA = (ushort_t*)carve((size_t)N * 256 * 2);  // bf16 gather table
    float* hB   = (float*)carve((size_t)N * 256 * 4);
    float* asrc = (float*)carve((size_t)N * 4 * 4);
    float* adst = (float*)carve((size_t)N * 4 * 4);
    float* sums = (float*)carve((size_t)G * 64 * 4);
    int*   cnts = (int*)carve((size_t)G * 4);
    int*   deg  = (int*)carve((size_t)N * 4);      // reused as scatter cursor
    int*   iptr = (int*)carve((size_t)(N + 1) * 4);
    int*   csr  = (int*)carve((size_t)M * 4);
    int*   bsum = (int*)carve(256 * 4);
    (void)ws_size; (void)n_in;

    const int NB = (N + 1023) / 1024;   // 49 blocks (<= 64)

    // -------- CSR build (shared by all 3 layers) --------
    hipMemsetAsync(deg, 0, (size_t)N * 4, stream);
    count_kernel<<<(M + 255) / 256, 256, 0, stream>>>(ei, deg, E, N);
    scan1_kernel<<<NB, 1024, 0, stream>>>(deg, iptr, bsum, N);
    scan2_kernel<<<1, 64, 0, stream>>>(bsum, NB);
    scan3_kernel<<<NB, 1024, 0, stream>>>(iptr, bsum, N);
    hipMemcpyAsync(deg, iptr, (size_t)N * 4, hipMemcpyDeviceToDevice, stream);
    scatter_kernel<<<(M + 255) / 256, 256, 0, stream>>>(ei, deg, csr, E, N);

    // -------- layer 1: x[N,128] -> hB[N,256] --------
    {
        dim3 grid((N + 127) / 128, 4);
        gemm_alpha_kernel<<<grid, 256, 0, stream>>>(x, W1, hA, as1, ad1, asrc, adst, N, IN_C, 256, 4);
    }
    aggregate4_kernel<<<(N + 3) / 4, 256, 0, stream>>>(hA, asrc, adst, iptr, csr, b1, hB, N, 1);

    // -------- layer 2: hB[N,256] -> hB[N,256] --------
    {
        dim3 grid((N + 127) / 128, 4);
        gemm_alpha_kernel<<<grid, 256, 0, stream>>>(hB, W2, hA, as2, ad2, asrc, adst, N, 256, 256, 4);
    }
    aggregate4_kernel<<<(N + 3) / 4, 256, 0, stream>>>(hA, asrc, adst, iptr, csr, b2, hB, N, 1);

    // -------- layer 3: hB[N,256] -> hB[N,64] (1 head, no ELU) --------
    {
        dim3 grid((N + 127) / 128, 1);
        gemm_alpha_kernel<<<grid, 256, 0, stream>>>(hB, W3, hA, as3, ad3, asrc, adst, N, 256, 64, 1);
    }
    aggregate_kernel<<<(N + 3) / 4, 256, 0, stream>>>(hA, asrc, adst, iptr, csr, b3, hB, N, 0);

    // -------- pool + classify --------
    hipMemsetAsync(sums, 0, (size_t)G * 64 * 4, stream);
    hipMemsetAsync(cnts, 0, (size_t)G * 4, stream);
    pool_kernel<<<(N + POOL_CHUNK - 1) / POOL_CHUNK, 64, 0, stream>>>(hB, bat, sums, cnts, N);
    classify_kernel<<<1, 640, 0, stream>>>(sums, cnts, Wc, bc, out, G);
}

// Round 7
// 485.243 us; speedup vs baseline: 2.0405x; 1.2580x over previous
//
#include <hip/hip_runtime.h>

#define NEG_SLOPE 0.2f
#define EPSV 1e-16f

typedef unsigned short ushort_t;
typedef __attribute__((ext_vector_type(8))) short bf16x8;
typedef __attribute__((ext_vector_type(4))) float f32x4;

__device__ __forceinline__ ushort_t f2bf(float f) {
    union { float f; unsigned u; } v; v.f = f;
    unsigned r = v.u + 0x7FFFu + ((v.u >> 16) & 1u);   // round-nearest-even
    return (ushort_t)(r >> 16);
}
__device__ __forceinline__ float bf2f(ushort_t u) {
    union { unsigned u; float f; } v; v.u = ((unsigned)u) << 16;
    return v.f;
}

// ---------------------------------------------------------------------------
// CSR build (by destination node), self-loops appended after the E real edges
// ---------------------------------------------------------------------------
__global__ __launch_bounds__(256)
void count_kernel(const int* __restrict__ ei, int* __restrict__ deg, int E, int n) {
    int i = blockIdx.x * blockDim.x + threadIdx.x;
    int M = E + n;
    if (i >= M) return;
    int d = (i < E) ? ei[E + i] : (i - E);
    atomicAdd(&deg[d], 1);
}

__global__ __launch_bounds__(1024)
void scan1_kernel(const int* __restrict__ deg, int* __restrict__ indptr,
                  int* __restrict__ bsum, int n) {
    __shared__ int wsum[16];
    const int t = threadIdx.x;
    const int lane = t & 63;
    const int w = t >> 6;
    const int i = blockIdx.x * 1024 + t;
    int v = (i < n) ? deg[i] : 0;
    int s = v;
    #pragma unroll
    for (int off = 1; off < 64; off <<= 1) {
        int u = __shfl_up(s, off);
        if (lane >= off) s += u;
    }
    if (lane == 63) wsum[w] = s;
    __syncthreads();
    if (t < 16) {
        int ws_ = wsum[t];
        #pragma unroll
        for (int off = 1; off < 16; off <<= 1) {
            int u = __shfl_up(ws_, off);
            if (t >= off) ws_ += u;
        }
        wsum[t] = ws_;
    }
    __syncthreads();
    int woff = (w > 0) ? wsum[w - 1] : 0;
    if (i < n) indptr[i + 1] = woff + s;
    if (t == 0) bsum[blockIdx.x] = wsum[15];
}

__global__ __launch_bounds__(64)
void scan2_kernel(int* __restrict__ bsum, int nb) {
    int t = threadIdx.x;
    int v = (t < nb) ? bsum[t] : 0;
    int s = v;
    #pragma unroll
    for (int off = 1; off < 64; off <<= 1) {
        int u = __shfl_up(s, off);
        if (t >= off) s += u;
    }
    if (t < nb) bsum[t] = s - v;
}

__global__ __launch_bounds__(1024)
void scan3_kernel(int* __restrict__ indptr, const int* __restrict__ bsum, int n) {
    int i = blockIdx.x * 1024 + threadIdx.x;
    if (i < n) indptr[i + 1] += bsum[blockIdx.x];
    if (i == 0) indptr[0] = 0;
}

__global__ __launch_bounds__(256)
void scatter_kernel(const int* __restrict__ ei, int* __restrict__ cursor,
                    int* __restrict__ csr_src, int E, int n) {
    int i = blockIdx.x * blockDim.x + threadIdx.x;
    int M = E + n;
    if (i >= M) return;
    int s, d;
    if (i < E) { s = ei[i]; d = ei[E + i]; }
    else       { s = i - E; d = i - E; }
    int pos = atomicAdd(&cursor[d], 1);
    csr_src[pos] = s;
}

// ---------------------------------------------------------------------------
// Pre-pass: fp32 -> bf16 convert; W[K][N] -> Wt[N][K] bf16 transpose
// ---------------------------------------------------------------------------
__global__ __launch_bounds__(256)
void cvt_kernel(const float* __restrict__ in, ushort_t* __restrict__ out, int n4) {
    int i = blockIdx.x * blockDim.x + threadIdx.x;
    if (i >= n4) return;
    float4 v = *reinterpret_cast<const float4*>(&in[i * 4]);
    ushort4 o;
    o.x = f2bf(v.x); o.y = f2bf(v.y); o.z = f2bf(v.z); o.w = f2bf(v.w);
    *reinterpret_cast<ushort4*>(&out[i * 4]) = o;
}

__global__ __launch_bounds__(256)
void transW_kernel(const float* __restrict__ W, ushort_t* __restrict__ Wt, int K, int N) {
    int idx = blockIdx.x * blockDim.x + threadIdx.x;
    if (idx >= K * N) return;
    int n = idx % N, k = idx / N;          // coalesced read of W
    Wt[(long)n * K + k] = f2bf(W[idx]);
}

// ---------------------------------------------------------------------------
// MFMA bf16 GEMM (128x64 tile, 4 waves, 2x4 16x16x32 frags/wave) + fused
// alpha epilogue. A=[M][K] bf16 row-major, Wt=[N][K] bf16 (K contiguous).
// One block column == one head (64 channels). C stored bf16.
// Fragment layout (guide §3 / m89): A: lane holds A[l&15][8*(l>>4)+j];
// C/D: col=l&15, row=(l>>4)*4+reg.
// ---------------------------------------------------------------------------
__global__ __launch_bounds__(256)
void mfma_gemm_alpha_kernel(const ushort_t* __restrict__ A, const ushort_t* __restrict__ Wt,
                            ushort_t* __restrict__ C,
                            const float* __restrict__ a_src, const float* __restrict__ a_dst,
                            float* __restrict__ asrc, float* __restrict__ adst,
                            int M, int K, int N, int H) {
    __shared__ ushort_t As[128][40];   // row stride 80B (16B-aligned, 2-way banks)
    __shared__ ushort_t Ws[64][40];
    const int tid = threadIdx.x;
    const int w   = tid >> 6;
    const int lane = tid & 63;
    const int l15 = lane & 15;
    const int l4  = lane >> 4;
    const int row0 = blockIdx.x * 128;
    const int col0 = blockIdx.y * 64;
    const int hd   = blockIdx.y;

    f32x4 acc[2][4];
    #pragma unroll
    for (int mi = 0; mi < 2; ++mi)
        #pragma unroll
        for (int ni = 0; ni < 4; ++ni)
            acc[mi][ni] = (f32x4){0.f, 0.f, 0.f, 0.f};

    for (int k0 = 0; k0 < K; k0 += 32) {
        // stage A: 128 rows x 32 k (2 x uint4 per thread)
        #pragma unroll
        for (int it = 0; it < 2; ++it) {
            int idx = tid + it * 256;
            int r = idx >> 2, seg = idx & 3;
            int gr = row0 + r;
            uint4 v = make_uint4(0u, 0u, 0u, 0u);
            if (gr < M)
                v = *reinterpret_cast<const uint4*>(&A[(long)gr * K + k0 + seg * 8]);
            *reinterpret_cast<uint4*>(&As[r][seg * 8]) = v;
        }
        // stage Wt: 64 rows x 32 k (1 x uint4 per thread)
        {
            int r = tid >> 2, seg = tid & 3;
            uint4 v = *reinterpret_cast<const uint4*>(&Wt[(long)(col0 + r) * K + k0 + seg * 8]);
            *reinterpret_cast<uint4*>(&Ws[r][seg * 8]) = v;
        }
        __syncthreads();
        bf16x8 af[2], bfr[4];
        #pragma unroll
        for (int mi = 0; mi < 2; ++mi)
            af[mi] = *reinterpret_cast<const bf16x8*>(&As[w * 32 + mi * 16 + l15][8 * l4]);
        #pragma unroll
        for (int ni = 0; ni < 4; ++ni)
            bfr[ni] = *reinterpret_cast<const bf16x8*>(&Ws[ni * 16 + l15][8 * l4]);
        #pragma unroll
        for (int mi = 0; mi < 2; ++mi)
            #pragma unroll
            for (int ni = 0; ni < 4; ++ni)
                acc[mi][ni] = __builtin_amdgcn_mfma_f32_16x16x32_bf16(
                    af[mi], bfr[ni], acc[mi][ni], 0, 0, 0);
        __syncthreads();
    }

    // ---- bf16 C store ----
    #pragma unroll
    for (int mi = 0; mi < 2; ++mi)
        #pragma unroll
        for (int reg = 0; reg < 4; ++reg) {
            int gr = row0 + w * 32 + mi * 16 + l4 * 4 + reg;
            if (gr < M) {
                #pragma unroll
                for (int ni = 0; ni < 4; ++ni)
                    C[(long)gr * N + col0 + ni * 16 + l15] = f2bf(acc[mi][ni][reg]);
            }
        }

    // ---- fused alpha epilogue (fp32-exact from accumulators) ----
    float aS[4], aD[4];
    #pragma unroll
    for (int ni = 0; ni < 4; ++ni) {
        aS[ni] = a_src[hd * 64 + ni * 16 + l15];
        aD[ni] = a_dst[hd * 64 + ni * 16 + l15];
    }
    #pragma unroll
    for (int mi = 0; mi < 2; ++mi)
        #pragma unroll
        for (int reg = 0; reg < 4; ++reg) {
            float s = 0.f, d = 0.f;
            #pragma unroll
            for (int ni = 0; ni < 4; ++ni) {
                s += acc[mi][ni][reg] * aS[ni];
                d += acc[mi][ni][reg] * aD[ni];
            }
            #pragma unroll
            for (int off = 1; off < 16; off <<= 1) {
                s += __shfl_xor(s, off);
                d += __shfl_xor(d, off);
            }
            int gr = row0 + w * 32 + mi * 16 + l4 * 4 + reg;
            if (l15 == 0 && gr < M) {
                asrc[gr * H + hd] = s;
                adst[gr * H + hd] = d;
            }
        }
}

// ---------------------------------------------------------------------------
// Aggregate, H=4: ONE wave per node; gather table h bf16 [N][256]; bf16 out.
// ---------------------------------------------------------------------------
__global__ __launch_bounds__(256)
void aggregate4_kernel(const ushort_t* __restrict__ h, const float* __restrict__ asrc,
                       const float* __restrict__ adst, const int* __restrict__ indptr,
                       const int* __restrict__ csr_src, const float* __restrict__ bias,
                       ushort_t* __restrict__ out, int n, int apply_elu) {
    __shared__ int   sOff[4][64];
    __shared__ float sEx[4][4][68];
    const int node = (blockIdx.x * blockDim.x + threadIdx.x) >> 6;
    const int lane = threadIdx.x & 63;
    const int w    = threadIdx.x >> 6;
    if (node >= n) return;
    const int hd   = lane >> 4;
    const int eidx = lane & 15;
    const int beg = indptr[node], end = indptr[node + 1];
    const float ad = adst[node * 4 + hd];
    const ushort_t* __restrict__ hrow = h + 4 * lane;

    float m = -3.4e38f, sum_ex = 0.f;
    float ax = 0.f, ay = 0.f, az = 0.f, aw = 0.f;
    for (int cb = beg; cb < end; cb += 64) {
        const int cnt = min(64, end - cb);
        int s[4];
        float e[4];
        #pragma unroll
        for (int j = 0; j < 4; ++j) {
            int idx = eidx + 16 * j;
            s[j] = (idx < cnt) ? csr_src[cb + idx] : 0;
        }
        #pragma unroll
        for (int j = 0; j < 4; ++j) {
            float t = asrc[s[j] * 4 + hd] + ad;
            t = t > 0.f ? t : NEG_SLOPE * t;
            e[j] = (eidx + 16 * j < cnt) ? t : -3.4e38f;
        }
        float cm = fmaxf(fmaxf(e[0], e[1]), fmaxf(e[2], e[3]));
        #pragma unroll
        for (int off = 1; off < 16; off <<= 1) cm = fmaxf(cm, __shfl_xor(cm, off));
        const float nm = fmaxf(m, cm);
        const float scale = __expf(m - nm);
        float ex[4];
        #pragma unroll
        for (int j = 0; j < 4; ++j)
            ex[j] = (eidx + 16 * j < cnt) ? __expf(e[j] - nm) : 0.f;
        float csum = (ex[0] + ex[1]) + (ex[2] + ex[3]);
        #pragma unroll
        for (int off = 1; off < 16; off <<= 1) csum += __shfl_xor(csum, off);
        sum_ex = sum_ex * scale + csum;
        ax *= scale; ay *= scale; az *= scale; aw *= scale;
        m = nm;
        #pragma unroll
        for (int j = 0; j < 4; ++j) sEx[w][hd][eidx + 16 * j] = ex[j];
        if (hd == 0) {
            #pragma unroll
            for (int j = 0; j < 4; ++j) sOff[w][eidx + 16 * j] = s[j] << 8;
        }
        int i = 0;
        for (; i + 8 <= cnt; i += 8) {
            int o[8];
            float ee[8];
            ushort4 v[8];
            #pragma unroll
            for (int u = 0; u < 8; ++u) o[u] = sOff[w][i + u];
            #pragma unroll
            for (int u = 0; u < 8; ++u) v[u] = *reinterpret_cast<const ushort4*>(hrow + o[u]);
            #pragma unroll
            for (int u = 0; u < 8; ++u) ee[u] = sEx[w][hd][i + u];
            #pragma unroll
            for (int u = 0; u < 8; ++u) {
                ax += ee[u] * bf2f(v[u].x);
                ay += ee[u] * bf2f(v[u].y);
                az += ee[u] * bf2f(v[u].z);
                aw += ee[u] * bf2f(v[u].w);
            }
        }
        for (; i < cnt; ++i) {
            int o = sOff[w][i];
            float ee = sEx[w][hd][i];
            ushort4 v = *reinterpret_cast<const ushort4*>(hrow + o);
            ax += ee * bf2f(v.x); ay += ee * bf2f(v.y);
            az += ee * bf2f(v.z); aw += ee * bf2f(v.w);
        }
    }
    const float inv = 1.f / (sum_ex + EPSV);
    float4 b4 = *reinterpret_cast<const float4*>(bias + 4 * lane);
    float ox = ax * inv + b4.x;
    float oy = ay * inv + b4.y;
    float oz = az * inv + b4.z;
    float ow = aw * inv + b4.w;
    if (apply_elu) {
        ox = ox > 0.f ? ox : expm1f(ox);
        oy = oy > 0.f ? oy : expm1f(oy);
        oz = oz > 0.f ? oz : expm1f(oz);
        ow = ow > 0.f ? ow : expm1f(ow);
    }
    ushort4 o4;
    o4.x = f2bf(ox); o4.y = f2bf(oy); o4.z = f2bf(oz); o4.w = f2bf(ow);
    *reinterpret_cast<ushort4*>(out + (long)node * 256 + 4 * lane) = o4;
}

// ---------------------------------------------------------------------------
// Aggregate, H=1: wave = 64 lanes = channels; h bf16 [N][64]; fp32 out.
// ---------------------------------------------------------------------------
__global__ __launch_bounds__(256)
void aggregate_kernel(const ushort_t* __restrict__ h, const float* __restrict__ asrc,
                      const float* __restrict__ adst, const int* __restrict__ indptr,
                      const int* __restrict__ csr_src, const float* __restrict__ bias,
                      float* __restrict__ out, int n, int apply_elu) {
    __shared__ int   sInd[4][64];
    __shared__ float sEx[4][64];
    const int node = (blockIdx.x * blockDim.x + threadIdx.x) >> 6;
    const int lane = threadIdx.x & 63;
    const int w    = threadIdx.x >> 6;
    if (node >= n) return;
    const int beg = indptr[node];
    const int end = indptr[node + 1];
    const float ad = adst[node];
    const ushort_t* __restrict__ hh = h + lane;

    float m = -3.4e38f, sum_ex = 0.f, acc = 0.f;
    for (int cb = beg; cb < end; cb += 64) {
        const int cnt = min(64, end - cb);
        int s = 0;
        float e = -3.4e38f;
        if (lane < cnt) {
            s = csr_src[cb + lane];
            e = asrc[s] + ad;
            e = e > 0.f ? e : NEG_SLOPE * e;
        }
        float cm = e;
        #pragma unroll
        for (int off = 32; off > 0; off >>= 1) cm = fmaxf(cm, __shfl_xor(cm, off));
        const float nm = fmaxf(m, cm);
        const float scale = __expf(m - nm);
        const float ex = (lane < cnt) ? __expf(e - nm) : 0.f;
        float cs = ex;
        #pragma unroll
        for (int off = 32; off > 0; off >>= 1) cs += __shfl_xor(cs, off);
        sum_ex = sum_ex * scale + cs;
        acc *= scale;
        m = nm;
        sInd[w][lane] = s;
        sEx[w][lane]  = ex;
        int i = 0;
        for (; i + 8 <= cnt; i += 8) {
            int si[8];
            float ei_[8], vi[8];
            #pragma unroll
            for (int u = 0; u < 8; ++u) si[u] = sInd[w][i + u];
            #pragma unroll
            for (int u = 0; u < 8; ++u) vi[u] = bf2f(hh[(long)si[u] * 64]);
            #pragma unroll
            for (int u = 0; u < 8; ++u) ei_[u] = sEx[w][i + u];
            #pragma unroll
            for (int u = 0; u < 8; ++u) acc += ei_[u] * vi[u];
        }
        for (; i < cnt; ++i)
            acc += sEx[w][i] * bf2f(hh[(long)sInd[w][i] * 64]);
    }
    float o = acc / (sum_ex + EPSV) + bias[lane];
    if (apply_elu) o = o > 0.f ? o : expm1f(o);
    out[(long)node * 64 + lane] = o;
}

// ---------------------------------------------------------------------------
// Global mean pool (batch is sorted) + classifier
// ---------------------------------------------------------------------------
constexpr int POOL_CHUNK = 128;

__global__ __launch_bounds__(64)
void pool_kernel(const float* __restrict__ h, const int* __restrict__ batch,
                 float* __restrict__ sums, int* __restrict__ counts, int n) {
    int lane = threadIdx.x;
    int start = blockIdx.x * POOL_CHUNK;
    if (start >= n) return;
    int end = min(start + POOL_CHUNK, n);
    int gcur = batch[start];
    float acc = 0.f;
    int run = 0;
    for (int i = start; i < end; ++i) {
        int g = batch[i];
        if (g != gcur) {
            atomicAdd(&sums[gcur * 64 + lane], acc);
            if (lane == 0) atomicAdd(&counts[gcur], run);
            acc = 0.f; run = 0; gcur = g;
        }
        acc += h[(long)i * 64 + lane];
        ++run;
    }
    atomicAdd(&sums[gcur * 64 + lane], acc);
    if (lane == 0) atomicAdd(&counts[gcur], run);
}

__global__ void classify_kernel(const float* __restrict__ sums, const int* __restrict__ counts,
                                const float* __restrict__ Wc, const float* __restrict__ bc,
                                float* __restrict__ out, int G) {
    int t = threadIdx.x;
    if (t >= G * 10) return;
    int g = t / 10, o = t - g * 10;
    int c_ = counts[g];
    float inv = 1.f / (float)(c_ > 1 ? c_ : 1);
    float acc = bc[o];
    for (int c = 0; c < 64; ++c)
        acc += sums[g * 64 + c] * inv * Wc[c * 10 + o];
    out[t] = acc;
}

// ---------------------------------------------------------------------------
extern "C" void kernel_launch(void* const* d_in, const int* in_sizes, int n_in,
                              void* d_out, int out_size, void* d_ws, size_t ws_size,
                              hipStream_t stream) {
    const float* x   = (const float*)d_in[0];
    const int*   ei  = (const int*)d_in[1];
    const int*   bat = (const int*)d_in[2];
    const float* W1  = (const float*)d_in[3];
    const float* as1 = (const float*)d_in[4];
    const float* ad1 = (const float*)d_in[5];
    const float* b1  = (const float*)d_in[6];
    const float* W2  = (const float*)d_in[7];
    const float* as2 = (const float*)d_in[8];
    const float* ad2 = (const float*)d_in[9];
    const float* b2  = (const float*)d_in[10];
    const float* W3  = (const float*)d_in[11];
    const float* as3 = (const float*)d_in[12];
    const float* ad3 = (const float*)d_in[13];
    const float* b3  = (const float*)d_in[14];
    const float* Wc  = (const float*)d_in[15];
    const float* bc  = (const float*)d_in[16];
    float* out = (float*)d_out;

    const int N = in_sizes[2];          // 50000 nodes
    const int E = in_sizes[1] / 2;      // 800000 edges
    const int M = E + N;                // + self loops
    const int IN_C = in_sizes[0] / N;   // 128
    const int G = out_size / 10;        // 64 graphs

    // -------- workspace carve (256B aligned) --------
    char* p = (char*)d_ws;
    auto carve = [&](size_t bytes) -> void* {
        void* r = (void*)p;
        p += (bytes + 255) & ~(size_t)255;
        return r;
    };
    ushort_t* hA  = (ushort_t*)carve((size_t)N * 256 * 2);  // GEMM out / gather
    ushort_t* hB  = (ushort_t*)carve((size_t)N * 256 * 2);  // aggregate out
    ushort_t* xb  = (ushort_t*)carve((size_t)N * IN_C * 2);
    ushort_t* Wt1 = (ushort_t*)carve((size_t)256 * IN_C * 2);
    ushort_t* Wt2 = (ushort_t*)carve((size_t)256 * 256 * 2);
    ushort_t* Wt3 = (ushort_t*)carve((size_t)64 * 256 * 2);
    float* h3f  = (float*)carve((size_t)N * 64 * 4);
    float* asrc = (float*)carve((size_t)N * 4 * 4);
    float* adst = (float*)carve((size_t)N * 4 * 4);
    float* sums = (float*)carve((size_t)G * 64 * 4);
    int*   cnts = (int*)carve((size_t)G * 4);
    int*   deg  = (int*)carve((size_t)N * 4);
    int*   iptr = (int*)carve((size_t)(N + 1) * 4);
    int*   csr  = (int*)carve((size_t)M * 4);
    int*   bsum = (int*)carve(256 * 4);
    (void)ws_size; (void)n_in;

    const int NB = (N + 1023) / 1024;

    // -------- input conversions (overlap-friendly, tiny) --------
    cvt_kernel<<<(N * IN_C / 4 + 255) / 256, 256, 0, stream>>>(x, xb, N * IN_C / 4);
    transW_kernel<<<(IN_C * 256 + 255) / 256, 256, 0, stream>>>(W1, Wt1, IN_C, 256);
    transW_kernel<<<(256 * 256 + 255) / 256, 256, 0, stream>>>(W2, Wt2, 256, 256);
    transW_kernel<<<(256 * 64 + 255) / 256, 256, 0, stream>>>(W3, Wt3, 256, 64);

    // -------- CSR build (shared by all 3 layers) --------
    hipMemsetAsync(deg, 0, (size_t)N * 4, stream);
    count_kernel<<<(M + 255) / 256, 256, 0, stream>>>(ei, deg, E, N);
    scan1_kernel<<<NB, 1024, 0, stream>>>(deg, iptr, bsum, N);
    scan2_kernel<<<1, 64, 0, stream>>>(bsum, NB);
    scan3_kernel<<<NB, 1024, 0, stream>>>(iptr, bsum, N);
    hipMemcpyAsync(deg, iptr, (size_t)N * 4, hipMemcpyDeviceToDevice, stream);
    scatter_kernel<<<(M + 255) / 256, 256, 0, stream>>>(ei, deg, csr, E, N);

    // -------- layer 1: xb[N,128] -> hB[N,256] --------
    {
        dim3 grid((N + 127) / 128, 4);
        mfma_gemm_alpha_kernel<<<grid, 256, 0, stream>>>(xb, Wt1, hA, as1, ad1,
                                                          asrc, adst, N, IN_C, 256, 4);
    }
    aggregate4_kernel<<<(N + 3) / 4, 256, 0, stream>>>(hA, asrc, adst, iptr, csr, b1, hB, N, 1);

    // -------- layer 2: hB[N,256] -> hB[N,256] --------
    {
        dim3 grid((N + 127) / 128, 4);
        mfma_gemm_alpha_kernel<<<grid, 256, 0, stream>>>(hB, Wt2, hA, as2, ad2,
                                                          asrc, adst, N, 256, 256, 4);
    }
    aggregate4_kernel<<<(N + 3) / 4, 256, 0, stream>>>(hA, asrc, adst, iptr, csr, b2, hB, N, 1);

    // -------- layer 3: hB[N,256] -> hA[N,64] (1 head, no ELU) --------
    {
        dim3 grid((N + 127) / 128, 1);
        mfma_gemm_alpha_kernel<<<grid, 256, 0, stream>>>(hB, Wt3, hA, as3, ad3,
                                                          asrc, adst, N, 256, 64, 1);
    }
    aggregate_kernel<<<(N + 3) / 4, 256, 0, stream>>>(hA, asrc, adst, iptr, csr, b3, h3f, N, 0);

    // -------- pool + classify --------
    hipMemsetAsync(sums, 0, (size_t)G * 64 * 4, stream);
    hipMemsetAsync(cnts, 0, (size_t)G * 4, stream);
    pool_kernel<<<(N + POOL_CHUNK - 1) / POOL_CHUNK, 64, 0, stream>>>(h3f, bat, sums, cnts, N);
    classify_kernel<<<1, 640, 0, stream>>>(sums, cnts, Wc, bc, out, G);
}

// Round 8
// 474.639 us; speedup vs baseline: 2.0861x; 1.0223x over previous
//
#include <hip/hip_runtime.h>

#define NEG_SLOPE 0.2f
#define EPSV 1e-16f

typedef unsigned short ushort_t;
typedef __attribute__((ext_vector_type(8))) short bf16x8;
typedef __attribute__((ext_vector_type(4))) float f32x4;

__device__ __forceinline__ ushort_t f2bf(float f) {
    union { float f; unsigned u; } v; v.f = f;
    unsigned r = v.u + 0x7FFFu + ((v.u >> 16) & 1u);   // round-nearest-even
    return (ushort_t)(r >> 16);
}
__device__ __forceinline__ float bf2f(ushort_t u) {
    union { unsigned u; float f; } v; v.u = ((unsigned)u) << 16;
    return v.f;
}

// ---------------------------------------------------------------------------
// CSR build (by destination node), self-loops appended after the E real edges
// ---------------------------------------------------------------------------
__global__ __launch_bounds__(256)
void count_kernel(const int* __restrict__ ei, int* __restrict__ deg, int E, int n) {
    int i = blockIdx.x * blockDim.x + threadIdx.x;
    int M = E + n;
    if (i >= M) return;
    int d = (i < E) ? ei[E + i] : (i - E);
    atomicAdd(&deg[d], 1);
}

__global__ __launch_bounds__(1024)
void scan1_kernel(const int* __restrict__ deg, int* __restrict__ indptr,
                  int* __restrict__ bsum, int n) {
    __shared__ int wsum[16];
    const int t = threadIdx.x;
    const int lane = t & 63;
    const int w = t >> 6;
    const int i = blockIdx.x * 1024 + t;
    int v = (i < n) ? deg[i] : 0;
    int s = v;
    #pragma unroll
    for (int off = 1; off < 64; off <<= 1) {
        int u = __shfl_up(s, off);
        if (lane >= off) s += u;
    }
    if (lane == 63) wsum[w] = s;
    __syncthreads();
    if (t < 16) {
        int ws_ = wsum[t];
        #pragma unroll
        for (int off = 1; off < 16; off <<= 1) {
            int u = __shfl_up(ws_, off);
            if (t >= off) ws_ += u;
        }
        wsum[t] = ws_;
    }
    __syncthreads();
    int woff = (w > 0) ? wsum[w - 1] : 0;
    if (i < n) indptr[i + 1] = woff + s;
    if (t == 0) bsum[blockIdx.x] = wsum[15];
}

__global__ __launch_bounds__(64)
void scan2_kernel(int* __restrict__ bsum, int nb) {
    int t = threadIdx.x;
    int v = (t < nb) ? bsum[t] : 0;
    int s = v;
    #pragma unroll
    for (int off = 1; off < 64; off <<= 1) {
        int u = __shfl_up(s, off);
        if (t >= off) s += u;
    }
    if (t < nb) bsum[t] = s - v;
}

__global__ __launch_bounds__(1024)
void scan3_kernel(int* __restrict__ indptr, const int* __restrict__ bsum, int n) {
    int i = blockIdx.x * 1024 + threadIdx.x;
    if (i < n) indptr[i + 1] += bsum[blockIdx.x];
    if (i == 0) indptr[0] = 0;
}

__global__ __launch_bounds__(256)
void scatter_kernel(const int* __restrict__ ei, int* __restrict__ cursor,
                    int* __restrict__ csr_src, int E, int n) {
    int i = blockIdx.x * blockDim.x + threadIdx.x;
    int M = E + n;
    if (i >= M) return;
    int s, d;
    if (i < E) { s = ei[i]; d = ei[E + i]; }
    else       { s = i - E; d = i - E; }
    int pos = atomicAdd(&cursor[d], 1);
    csr_src[pos] = s;
}

// ---------------------------------------------------------------------------
// Prep: x -> bf16; W1/W2/W3 -> transposed bf16 (one kernel, sectioned)
// ---------------------------------------------------------------------------
__global__ __launch_bounds__(256)
void prep_kernel(const float* __restrict__ x, ushort_t* __restrict__ xb, int nx4,
                 const float* __restrict__ W1, ushort_t* __restrict__ Wt1,
                 const float* __restrict__ W2, ushort_t* __restrict__ Wt2,
                 const float* __restrict__ W3, ushort_t* __restrict__ Wt3,
                 int K1) {
    long idx = (long)blockIdx.x * 256 + threadIdx.x;
    if (idx < nx4) {
        float4 v = *reinterpret_cast<const float4*>(&x[idx * 4]);
        ushort4 o;
        o.x = f2bf(v.x); o.y = f2bf(v.y); o.z = f2bf(v.z); o.w = f2bf(v.w);
        *reinterpret_cast<ushort4*>(&xb[idx * 4]) = o;
        return;
    }
    idx -= nx4;
    if (idx < (long)K1 * 256) {       // W1: [K1][256]
        int n = (int)(idx % 256), k = (int)(idx / 256);
        Wt1[(long)n * K1 + k] = f2bf(W1[idx]);
        return;
    }
    idx -= (long)K1 * 256;
    if (idx < 256 * 256) {            // W2: [256][256]
        int n = (int)(idx % 256), k = (int)(idx / 256);
        Wt2[(long)n * 256 + k] = f2bf(W2[idx]);
        return;
    }
    idx -= 256 * 256;
    if (idx < 256 * 64) {             // W3: [256][64]
        int n = (int)(idx % 64), k = (int)(idx / 64);
        Wt3[(long)n * 256 + k] = f2bf(W3[idx]);
    }
}

// ---------------------------------------------------------------------------
// MFMA bf16 GEMM, 128 x (NC*64) tile, 4 waves, fused alpha epilogue.
// NC=2: waves 2x2, each 64x64 (4x4 frags). NC=1: waves 4x1, each 32x64 (2x4).
// A=[M][K] bf16, Wt=[N][K] bf16. C bf16. Each wave's 64-col span = 1 head.
// ---------------------------------------------------------------------------
template<int NC>
__global__ __launch_bounds__(256)
void mfma_gemm_alpha_kernel(const ushort_t* __restrict__ A, const ushort_t* __restrict__ Wt,
                            ushort_t* __restrict__ C,
                            const float* __restrict__ a_src, const float* __restrict__ a_dst,
                            float* __restrict__ asrc, float* __restrict__ adst,
                            int M, int K, int N, int H) {
    constexpr int TBN = NC * 64;
    constexpr int MI  = (NC == 2) ? 4 : 2;
    __shared__ ushort_t As[128][40];   // 80B row stride: ~2-way banks (free)
    __shared__ ushort_t Ws[TBN][40];
    const int tid  = threadIdx.x;
    const int w    = tid >> 6;
    const int lane = tid & 63;
    const int l15  = lane & 15;
    const int l4   = lane >> 4;
    const int row0 = blockIdx.x * 128;
    const int col0 = blockIdx.y * TBN;
    const int rbase = (NC == 2) ? (w & 1) * 64 : w * 32;
    const int cbase = (NC == 2) ? (w >> 1) * 64 : 0;

    f32x4 acc[MI][4];
    #pragma unroll
    for (int mi = 0; mi < MI; ++mi)
        #pragma unroll
        for (int ni = 0; ni < 4; ++ni)
            acc[mi][ni] = (f32x4){0.f, 0.f, 0.f, 0.f};

    for (int k0 = 0; k0 < K; k0 += 32) {
        // stage A: 128 rows x 32 k = 512 uint4 slots
        #pragma unroll
        for (int it = 0; it < 2; ++it) {
            int idx = tid + it * 256;
            int r = idx >> 2, seg = idx & 3;
            int gr = row0 + r;
            uint4 v = make_uint4(0u, 0u, 0u, 0u);
            if (gr < M)
                v = *reinterpret_cast<const uint4*>(&A[(long)gr * K + k0 + seg * 8]);
            *reinterpret_cast<uint4*>(&As[r][seg * 8]) = v;
        }
        // stage Ws: TBN rows x 32 k
        #pragma unroll
        for (int it = 0; it < NC; ++it) {
            int idx = tid + it * 256;
            int r = idx >> 2, seg = idx & 3;
            uint4 v = *reinterpret_cast<const uint4*>(&Wt[(long)(col0 + r) * K + k0 + seg * 8]);
            *reinterpret_cast<uint4*>(&Ws[r][seg * 8]) = v;
        }
        __syncthreads();
        bf16x8 af[MI], bfv[4];
        #pragma unroll
        for (int mi = 0; mi < MI; ++mi)
            af[mi] = *reinterpret_cast<const bf16x8*>(&As[rbase + mi * 16 + l15][8 * l4]);
        #pragma unroll
        for (int ni = 0; ni < 4; ++ni)
            bfv[ni] = *reinterpret_cast<const bf16x8*>(&Ws[cbase + ni * 16 + l15][8 * l4]);
        #pragma unroll
        for (int mi = 0; mi < MI; ++mi)
            #pragma unroll
            for (int ni = 0; ni < 4; ++ni)
                acc[mi][ni] = __builtin_amdgcn_mfma_f32_16x16x32_bf16(
                    af[mi], bfv[ni], acc[mi][ni], 0, 0, 0);
        __syncthreads();
    }

    // ---- bf16 C store ----
    #pragma unroll
    for (int mi = 0; mi < MI; ++mi)
        #pragma unroll
        for (int reg = 0; reg < 4; ++reg) {
            int gr = row0 + rbase + mi * 16 + l4 * 4 + reg;
            if (gr < M) {
                #pragma unroll
                for (int ni = 0; ni < 4; ++ni)
                    C[(long)gr * N + col0 + cbase + ni * 16 + l15] = f2bf(acc[mi][ni][reg]);
            }
        }

    // ---- fused alpha epilogue (fp32-exact from accumulators) ----
    const int hd = (col0 + cbase) >> 6;
    float aS[4], aD[4];
    #pragma unroll
    for (int ni = 0; ni < 4; ++ni) {
        aS[ni] = a_src[hd * 64 + ni * 16 + l15];
        aD[ni] = a_dst[hd * 64 + ni * 16 + l15];
    }
    #pragma unroll
    for (int mi = 0; mi < MI; ++mi)
        #pragma unroll
        for (int reg = 0; reg < 4; ++reg) {
            float s = 0.f, d = 0.f;
            #pragma unroll
            for (int ni = 0; ni < 4; ++ni) {
                s += acc[mi][ni][reg] * aS[ni];
                d += acc[mi][ni][reg] * aD[ni];
            }
            #pragma unroll
            for (int off = 1; off < 16; off <<= 1) {
                s += __shfl_xor(s, off);
                d += __shfl_xor(d, off);
            }
            int gr = row0 + rbase + mi * 16 + l4 * 4 + reg;
            if (l15 == 0 && gr < M) {
                asrc[gr * H + hd] = s;
                adst[gr * H + hd] = d;
            }
        }
}

// ---------------------------------------------------------------------------
// Aggregate, H=4: ONE wave per node; h bf16 [N][256]; bf16 out.
// No max-subtraction: exp(e)/sum(exp(e)) (identical math; |e| << 88 here).
// ---------------------------------------------------------------------------
__global__ __launch_bounds__(256)
void aggregate4_kernel(const ushort_t* __restrict__ h, const float* __restrict__ asrc,
                       const float* __restrict__ adst, const int* __restrict__ indptr,
                       const int* __restrict__ csr_src, const float* __restrict__ bias,
                       ushort_t* __restrict__ out, int n, int apply_elu) {
    __shared__ int   sOff[4][64];
    __shared__ float sEx[4][4][68];
    const int node = (blockIdx.x * blockDim.x + threadIdx.x) >> 6;
    const int lane = threadIdx.x & 63;
    const int w    = threadIdx.x >> 6;
    if (node >= n) return;
    const int hd   = lane >> 4;
    const int eidx = lane & 15;
    const int beg = indptr[node], end = indptr[node + 1];
    const float ad = adst[node * 4 + hd];
    const ushort_t* __restrict__ hrow = h + 4 * lane;

    float sum_ex = 0.f;
    float ax = 0.f, ay = 0.f, az = 0.f, aw = 0.f;
    for (int cb = beg; cb < end; cb += 64) {
        const int cnt = min(64, end - cb);
        // ---- pass A: e -> exp(e), no max machinery ----
        int s[4];
        float ex[4];
        #pragma unroll
        for (int j = 0; j < 4; ++j) {
            int idx = eidx + 16 * j;
            s[j] = (idx < cnt) ? csr_src[cb + idx] : 0;
        }
        #pragma unroll
        for (int j = 0; j < 4; ++j) {
            float t = asrc[s[j] * 4 + hd] + ad;
            t = t > 0.f ? t : NEG_SLOPE * t;
            ex[j] = (eidx + 16 * j < cnt) ? __expf(t) : 0.f;
        }
        float csum = (ex[0] + ex[1]) + (ex[2] + ex[3]);
        #pragma unroll
        for (int off = 1; off < 16; off <<= 1) csum += __shfl_xor(csum, off);
        sum_ex += csum;
        #pragma unroll
        for (int j = 0; j < 4; ++j) sEx[w][hd][eidx + 16 * j] = ex[j];
        if (hd == 0) {
            #pragma unroll
            for (int j = 0; j < 4; ++j) sOff[w][eidx + 16 * j] = s[j] << 8;
        }
        // ---- pass B: gather bf16 rows, 8 loads in flight ----
        int i = 0;
        for (; i + 8 <= cnt; i += 8) {
            int o[8];
            float ee[8];
            ushort4 v[8];
            #pragma unroll
            for (int u = 0; u < 8; ++u) o[u] = sOff[w][i + u];
            #pragma unroll
            for (int u = 0; u < 8; ++u) v[u] = *reinterpret_cast<const ushort4*>(hrow + o[u]);
            #pragma unroll
            for (int u = 0; u < 8; ++u) ee[u] = sEx[w][hd][i + u];
            #pragma unroll
            for (int u = 0; u < 8; ++u) {
                ax += ee[u] * bf2f(v[u].x);
                ay += ee[u] * bf2f(v[u].y);
                az += ee[u] * bf2f(v[u].z);
                aw += ee[u] * bf2f(v[u].w);
            }
        }
        for (; i < cnt; ++i) {
            int o = sOff[w][i];
            float ee = sEx[w][hd][i];
            ushort4 v = *reinterpret_cast<const ushort4*>(hrow + o);
            ax += ee * bf2f(v.x); ay += ee * bf2f(v.y);
            az += ee * bf2f(v.z); aw += ee * bf2f(v.w);
        }
    }
    const float inv = 1.f / (sum_ex + EPSV);
    float4 b4 = *reinterpret_cast<const float4*>(bias + 4 * lane);
    float ox = ax * inv + b4.x;
    float oy = ay * inv + b4.y;
    float oz = az * inv + b4.z;
    float ow = aw * inv + b4.w;
    if (apply_elu) {
        ox = ox > 0.f ? ox : expm1f(ox);
        oy = oy > 0.f ? oy : expm1f(oy);
        oz = oz > 0.f ? oz : expm1f(oz);
        ow = ow > 0.f ? ow : expm1f(ow);
    }
    ushort4 o4;
    o4.x = f2bf(ox); o4.y = f2bf(oy); o4.z = f2bf(oz); o4.w = f2bf(ow);
    *reinterpret_cast<ushort4*>(out + (long)node * 256 + 4 * lane) = o4;
}

// ---------------------------------------------------------------------------
// Aggregate, H=1: wave = 64 lanes = channels; h bf16 [N][64]; bf16 out.
// ---------------------------------------------------------------------------
__global__ __launch_bounds__(256)
void aggregate_kernel(const ushort_t* __restrict__ h, const float* __restrict__ asrc,
                      const float* __restrict__ adst, const int* __restrict__ indptr,
                      const int* __restrict__ csr_src, const float* __restrict__ bias,
                      ushort_t* __restrict__ out, int n, int apply_elu) {
    __shared__ int   sInd[4][64];
    __shared__ float sEx[4][64];
    const int node = (blockIdx.x * blockDim.x + threadIdx.x) >> 6;
    const int lane = threadIdx.x & 63;
    const int w    = threadIdx.x >> 6;
    if (node >= n) return;
    const int beg = indptr[node];
    const int end = indptr[node + 1];
    const float ad = adst[node];
    const ushort_t* __restrict__ hh = h + lane;

    float sum_ex = 0.f, acc = 0.f;
    for (int cb = beg; cb < end; cb += 64) {
        const int cnt = min(64, end - cb);
        int s = 0;
        float ex = 0.f;
        if (lane < cnt) {
            s = csr_src[cb + lane];
            float e = asrc[s] + ad;
            e = e > 0.f ? e : NEG_SLOPE * e;
            ex = __expf(e);
        }
        float cs = ex;
        #pragma unroll
        for (int off = 32; off > 0; off >>= 1) cs += __shfl_xor(cs, off);
        sum_ex += cs;
        sInd[w][lane] = s;
        sEx[w][lane]  = ex;
        int i = 0;
        for (; i + 8 <= cnt; i += 8) {
            int si[8];
            float ei_[8], vi[8];
            #pragma unroll
            for (int u = 0; u < 8; ++u) si[u] = sInd[w][i + u];
            #pragma unroll
            for (int u = 0; u < 8; ++u) vi[u] = bf2f(hh[(long)si[u] * 64]);
            #pragma unroll
            for (int u = 0; u < 8; ++u) ei_[u] = sEx[w][i + u];
            #pragma unroll
            for (int u = 0; u < 8; ++u) acc += ei_[u] * vi[u];
        }
        for (; i < cnt; ++i)
            acc += sEx[w][i] * bf2f(hh[(long)sInd[w][i] * 64]);
    }
    float o = acc / (sum_ex + EPSV) + bias[lane];
    if (apply_elu) o = o > 0.f ? o : expm1f(o);
    out[(long)node * 64 + lane] = f2bf(o);
}

// ---------------------------------------------------------------------------
// Global mean pool (batch is sorted, bf16 input) + classifier
// ---------------------------------------------------------------------------
constexpr int POOL_CHUNK = 128;

__global__ __launch_bounds__(64)
void pool_kernel(const ushort_t* __restrict__ h, const int* __restrict__ batch,
                 float* __restrict__ sums, int* __restrict__ counts, int n) {
    int lane = threadIdx.x;
    int start = blockIdx.x * POOL_CHUNK;
    if (start >= n) return;
    int end = min(start + POOL_CHUNK, n);
    int gcur = batch[start];
    float acc = 0.f;
    int run = 0;
    for (int i = start; i < end; ++i) {
        int g = batch[i];
        if (g != gcur) {
            atomicAdd(&sums[gcur * 64 + lane], acc);
            if (lane == 0) atomicAdd(&counts[gcur], run);
            acc = 0.f; run = 0; gcur = g;
        }
        acc += bf2f(h[(long)i * 64 + lane]);
        ++run;
    }
    atomicAdd(&sums[gcur * 64 + lane], acc);
    if (lane == 0) atomicAdd(&counts[gcur], run);
}

__global__ void classify_kernel(const float* __restrict__ sums, const int* __restrict__ counts,
                                const float* __restrict__ Wc, const float* __restrict__ bc,
                                float* __restrict__ out, int G) {
    int t = threadIdx.x;
    if (t >= G * 10) return;
    int g = t / 10, o = t - g * 10;
    int c_ = counts[g];
    float inv = 1.f / (float)(c_ > 1 ? c_ : 1);
    float acc = bc[o];
    for (int c = 0; c < 64; ++c)
        acc += sums[g * 64 + c] * inv * Wc[c * 10 + o];
    out[t] = acc;
}

// ---------------------------------------------------------------------------
extern "C" void kernel_launch(void* const* d_in, const int* in_sizes, int n_in,
                              void* d_out, int out_size, void* d_ws, size_t ws_size,
                              hipStream_t stream) {
    const float* x   = (const float*)d_in[0];
    const int*   ei  = (const int*)d_in[1];
    const int*   bat = (const int*)d_in[2];
    const float* W1  = (const float*)d_in[3];
    const float* as1 = (const float*)d_in[4];
    const float* ad1 = (const float*)d_in[5];
    const float* b1  = (const float*)d_in[6];
    const float* W2  = (const float*)d_in[7];
    const float* as2 = (const float*)d_in[8];
    const float* ad2 = (const float*)d_in[9];
    const float* b2  = (const float*)d_in[10];
    const float* W3  = (const float*)d_in[11];
    const float* as3 = (const float*)d_in[12];
    const float* ad3 = (const float*)d_in[13];
    const float* b3  = (const float*)d_in[14];
    const float* Wc  = (const float*)d_in[15];
    const float* bc  = (const float*)d_in[16];
    float* out = (float*)d_out;

    const int N = in_sizes[2];          // 50000 nodes
    const int E = in_sizes[1] / 2;      // 800000 edges
    const int M = E + N;                // + self loops
    const int IN_C = in_sizes[0] / N;   // 128
    const int G = out_size / 10;        // 64 graphs

    // -------- workspace carve (256B aligned) --------
    char* p = (char*)d_ws;
    auto carve = [&](size_t bytes) -> void* {
        void* r = (void*)p;
        p += (bytes + 255) & ~(size_t)255;
        return r;
    };
    ushort_t* hA  = (ushort_t*)carve((size_t)N * 256 * 2);  // GEMM out / gather
    ushort_t* hB  = (ushort_t*)carve((size_t)N * 256 * 2);  // aggregate out
    ushort_t* xb  = (ushort_t*)carve((size_t)N * IN_C * 2);
    ushort_t* Wt1 = (ushort_t*)carve((size_t)256 * IN_C * 2);
    ushort_t* Wt2 = (ushort_t*)carve((size_t)256 * 256 * 2);
    ushort_t* Wt3 = (ushort_t*)carve((size_t)64 * 256 * 2);
    float* asrc = (float*)carve((size_t)N * 4 * 4);
    float* adst = (float*)carve((size_t)N * 4 * 4);
    float* sums = (float*)carve((size_t)G * 64 * 4);
    int*   cnts = (int*)carve((size_t)G * 4);
    int*   deg  = (int*)carve((size_t)N * 4);
    int*   iptr = (int*)carve((size_t)(N + 1) * 4);
    int*   csr  = (int*)carve((size_t)M * 4);
    int*   bsum = (int*)carve(256 * 4);
    (void)ws_size; (void)n_in;

    const int NB = (N + 1023) / 1024;

    // -------- prep (cvt + 3x transW in one kernel) --------
    {
        long nx4 = (long)N * IN_C / 4;
        long total = nx4 + (long)IN_C * 256 + 256 * 256 + 256 * 64;
        prep_kernel<<<(int)((total + 255) / 256), 256, 0, stream>>>(
            x, xb, (int)nx4, W1, Wt1, W2, Wt2, W3, Wt3, IN_C);
    }

    // -------- CSR build (shared by all 3 layers) --------
    hipMemsetAsync(deg, 0, (size_t)N * 4, stream);
    count_kernel<<<(M + 255) / 256, 256, 0, stream>>>(ei, deg, E, N);
    scan1_kernel<<<NB, 1024, 0, stream>>>(deg, iptr, bsum, N);
    scan2_kernel<<<1, 64, 0, stream>>>(bsum, NB);
    scan3_kernel<<<NB, 1024, 0, stream>>>(iptr, bsum, N);
    hipMemcpyAsync(deg, iptr, (size_t)N * 4, hipMemcpyDeviceToDevice, stream);
    scatter_kernel<<<(M + 255) / 256, 256, 0, stream>>>(ei, deg, csr, E, N);

    // -------- layer 1: xb[N,128] -> hB[N,256] --------
    {
        dim3 grid((N + 127) / 128, 2);
        mfma_gemm_alpha_kernel<2><<<grid, 256, 0, stream>>>(xb, Wt1, hA, as1, ad1,
                                                            asrc, adst, N, IN_C, 256, 4);
    }
    aggregate4_kernel<<<(N + 3) / 4, 256, 0, stream>>>(hA, asrc, adst, iptr, csr, b1, hB, N, 1);

    // -------- layer 2: hB[N,256] -> hB[N,256] --------
    {
        dim3 grid((N + 127) / 128, 2);
        mfma_gemm_alpha_kernel<2><<<grid, 256, 0, stream>>>(hB, Wt2, hA, as2, ad2,
                                                            asrc, adst, N, 256, 256, 4);
    }
    aggregate4_kernel<<<(N + 3) / 4, 256, 0, stream>>>(hA, asrc, adst, iptr, csr, b2, hB, N, 1);

    // -------- layer 3: hB[N,256] -> hA[N,64] (1 head, no ELU) --------
    {
        dim3 grid((N + 127) / 128, 1);
        mfma_gemm_alpha_kernel<1><<<grid, 256, 0, stream>>>(hB, Wt3, hA, as3, ad3,
                                                            asrc, adst, N, 256, 64, 1);
    }
    aggregate_kernel<<<(N + 3) / 4, 256, 0, stream>>>(hA, asrc, adst, iptr, csr, b3, hB, N, 0);

    // -------- pool + classify --------
    hipMemsetAsync(sums, 0, (size_t)G * 64 * 4, stream);
    hipMemsetAsync(cnts, 0, (size_t)G * 4, stream);
    pool_kernel<<<(N + POOL_CHUNK - 1) / POOL_CHUNK, 64, 0, stream>>>(hB, bat, sums, cnts, N);
    classify_kernel<<<1, 640, 0, stream>>>(sums, cnts, Wc, bc, out, G);
}

// Round 9
// 448.015 us; speedup vs baseline: 2.2100x; 1.0594x over previous
//
#include <hip/hip_runtime.h>

#define NEG_SLOPE 0.2f
#define EPSV 1e-16f

typedef unsigned short ushort_t;
typedef unsigned char uchar_t;
typedef __attribute__((ext_vector_type(8))) short bf16x8;
typedef __attribute__((ext_vector_type(4))) float f32x4;
typedef __attribute__((ext_vector_type(2))) float f32x2;

__device__ __forceinline__ ushort_t f2bf(float f) {
    union { float f; unsigned u; } v; v.f = f;
    unsigned r = v.u + 0x7FFFu + ((v.u >> 16) & 1u);   // round-nearest-even
    return (ushort_t)(r >> 16);
}
__device__ __forceinline__ float bf2f(ushort_t u) {
    union { unsigned u; float f; } v; v.u = ((unsigned)u) << 16;
    return v.f;
}
__device__ __forceinline__ uchar_t f2fp8(float f) {
    int p = __builtin_amdgcn_cvt_pk_fp8_f32(f, 0.f, 0, false);  // OCP e4m3 on gfx950
    return (uchar_t)(p & 0xff);
}

// ---------------------------------------------------------------------------
// CSR build (by destination node), self-loops appended after the E real edges
// ---------------------------------------------------------------------------
__global__ __launch_bounds__(256)
void count_kernel(const int* __restrict__ ei, int* __restrict__ deg, int E, int n) {
    int i = blockIdx.x * blockDim.x + threadIdx.x;
    int M = E + n;
    if (i >= M) return;
    int d = (i < E) ? ei[E + i] : (i - E);
    atomicAdd(&deg[d], 1);
}

__global__ __launch_bounds__(1024)
void scan1_kernel(const int* __restrict__ deg, int* __restrict__ indptr,
                  int* __restrict__ bsum, int n) {
    __shared__ int wsum[16];
    const int t = threadIdx.x;
    const int lane = t & 63;
    const int w = t >> 6;
    const int i = blockIdx.x * 1024 + t;
    int v = (i < n) ? deg[i] : 0;
    int s = v;
    #pragma unroll
    for (int off = 1; off < 64; off <<= 1) {
        int u = __shfl_up(s, off);
        if (lane >= off) s += u;
    }
    if (lane == 63) wsum[w] = s;
    __syncthreads();
    if (t < 16) {
        int ws_ = wsum[t];
        #pragma unroll
        for (int off = 1; off < 16; off <<= 1) {
            int u = __shfl_up(ws_, off);
            if (t >= off) ws_ += u;
        }
        wsum[t] = ws_;
    }
    __syncthreads();
    int woff = (w > 0) ? wsum[w - 1] : 0;
    if (i < n) indptr[i + 1] = woff + s;
    if (t == 0) bsum[blockIdx.x] = wsum[15];
}

// scan3: in-kernel exclusive prefix of bsum (<=64 blocks) + finalize indptr,
// and write the scatter cursor copy (replaces scan2 kernel + D2D memcpy).
__global__ __launch_bounds__(1024)
void scan3_kernel(int* __restrict__ indptr, int* __restrict__ cursor,
                  const int* __restrict__ bsum, int nb, int n) {
    __shared__ int boff_s;
    const int t = threadIdx.x;
    if (t < 64) {
        int v = (t < nb) ? bsum[t] : 0;
        int s = v;
        #pragma unroll
        for (int off = 1; off < 64; off <<= 1) {
            int u = __shfl_up(s, off);
            if (t >= off) s += u;
        }
        if (t == (int)blockIdx.x) boff_s = s - v;   // exclusive prefix
    }
    __syncthreads();
    const int boff = boff_s;
    int i = blockIdx.x * 1024 + t;
    if (i < n) {
        int val = indptr[i + 1] + boff;
        indptr[i + 1] = val;
        cursor[i + 1] = val;
    }
    if (i == 0) { indptr[0] = 0; cursor[0] = 0; }
}

__global__ __launch_bounds__(256)
void scatter_kernel(const int* __restrict__ ei, int* __restrict__ cursor,
                    int* __restrict__ csr_src, int E, int n) {
    int i = blockIdx.x * blockDim.x + threadIdx.x;
    int M = E + n;
    if (i >= M) return;
    int s, d;
    if (i < E) { s = ei[i]; d = ei[E + i]; }
    else       { s = i - E; d = i - E; }
    int pos = atomicAdd(&cursor[d], 1);
    csr_src[pos] = s;
}

// ---------------------------------------------------------------------------
// Prep: x -> bf16; W1/W2/W3 -> transposed bf16; zero deg (one kernel)
// ---------------------------------------------------------------------------
__global__ __launch_bounds__(256)
void prep_kernel(const float* __restrict__ x, ushort_t* __restrict__ xb, int nx4,
                 const float* __restrict__ W1, ushort_t* __restrict__ Wt1,
                 const float* __restrict__ W2, ushort_t* __restrict__ Wt2,
                 const float* __restrict__ W3, ushort_t* __restrict__ Wt3,
                 int K1, int* __restrict__ deg, int n) {
    long idx = (long)blockIdx.x * 256 + threadIdx.x;
    if (idx < nx4) {
        float4 v = *reinterpret_cast<const float4*>(&x[idx * 4]);
        ushort4 o;
        o.x = f2bf(v.x); o.y = f2bf(v.y); o.z = f2bf(v.z); o.w = f2bf(v.w);
        *reinterpret_cast<ushort4*>(&xb[idx * 4]) = o;
        return;
    }
    idx -= nx4;
    if (idx < (long)K1 * 256) {       // W1: [K1][256]
        int c = (int)(idx % 256), k = (int)(idx / 256);
        Wt1[(long)c * K1 + k] = f2bf(W1[idx]);
        return;
    }
    idx -= (long)K1 * 256;
    if (idx < 256 * 256) {            // W2: [256][256]
        int c = (int)(idx % 256), k = (int)(idx / 256);
        Wt2[(long)c * 256 + k] = f2bf(W2[idx]);
        return;
    }
    idx -= 256 * 256;
    if (idx < 256 * 64) {             // W3: [256][64]
        int c = (int)(idx % 64), k = (int)(idx / 64);
        Wt3[(long)c * 256 + k] = f2bf(W3[idx]);
        return;
    }
    idx -= 256 * 64;
    if (idx < n) deg[idx] = 0;        // zero degree counters
}

// ---------------------------------------------------------------------------
// MFMA bf16 GEMM, 128 x (NC*64) tile, 4 waves, fused alpha epilogue.
// C stored fp8 e4m3 (gather table). Alpha from fp32 accumulators (exact).
// ---------------------------------------------------------------------------
template<int NC>
__global__ __launch_bounds__(256)
void mfma_gemm_alpha_kernel(const ushort_t* __restrict__ A, const ushort_t* __restrict__ Wt,
                            uchar_t* __restrict__ C,
                            const float* __restrict__ a_src, const float* __restrict__ a_dst,
                            float* __restrict__ asrc, float* __restrict__ adst,
                            int M, int K, int N, int H) {
    constexpr int TBN = NC * 64;
    constexpr int MI  = (NC == 2) ? 4 : 2;
    __shared__ ushort_t As[128][40];
    __shared__ ushort_t Ws[TBN][40];
    const int tid  = threadIdx.x;
    const int w    = tid >> 6;
    const int lane = tid & 63;
    const int l15  = lane & 15;
    const int l4   = lane >> 4;
    const int row0 = blockIdx.x * 128;
    const int col0 = blockIdx.y * TBN;
    const int rbase = (NC == 2) ? (w & 1) * 64 : w * 32;
    const int cbase = (NC == 2) ? (w >> 1) * 64 : 0;

    f32x4 acc[MI][4];
    #pragma unroll
    for (int mi = 0; mi < MI; ++mi)
        #pragma unroll
        for (int ni = 0; ni < 4; ++ni)
            acc[mi][ni] = (f32x4){0.f, 0.f, 0.f, 0.f};

    for (int k0 = 0; k0 < K; k0 += 32) {
        #pragma unroll
        for (int it = 0; it < 2; ++it) {
            int idx = tid + it * 256;
            int r = idx >> 2, seg = idx & 3;
            int gr = row0 + r;
            uint4 v = make_uint4(0u, 0u, 0u, 0u);
            if (gr < M)
                v = *reinterpret_cast<const uint4*>(&A[(long)gr * K + k0 + seg * 8]);
            *reinterpret_cast<uint4*>(&As[r][seg * 8]) = v;
        }
        #pragma unroll
        for (int it = 0; it < NC; ++it) {
            int idx = tid + it * 256;
            int r = idx >> 2, seg = idx & 3;
            uint4 v = *reinterpret_cast<const uint4*>(&Wt[(long)(col0 + r) * K + k0 + seg * 8]);
            *reinterpret_cast<uint4*>(&Ws[r][seg * 8]) = v;
        }
        __syncthreads();
        bf16x8 af[MI], bfv[4];
        #pragma unroll
        for (int mi = 0; mi < MI; ++mi)
            af[mi] = *reinterpret_cast<const bf16x8*>(&As[rbase + mi * 16 + l15][8 * l4]);
        #pragma unroll
        for (int ni = 0; ni < 4; ++ni)
            bfv[ni] = *reinterpret_cast<const bf16x8*>(&Ws[cbase + ni * 16 + l15][8 * l4]);
        #pragma unroll
        for (int mi = 0; mi < MI; ++mi)
            #pragma unroll
            for (int ni = 0; ni < 4; ++ni)
                acc[mi][ni] = __builtin_amdgcn_mfma_f32_16x16x32_bf16(
                    af[mi], bfv[ni], acc[mi][ni], 0, 0, 0);
        __syncthreads();
    }

    // ---- fp8 C store ----
    #pragma unroll
    for (int mi = 0; mi < MI; ++mi)
        #pragma unroll
        for (int reg = 0; reg < 4; ++reg) {
            int gr = row0 + rbase + mi * 16 + l4 * 4 + reg;
            if (gr < M) {
                #pragma unroll
                for (int ni = 0; ni < 4; ++ni)
                    C[(long)gr * N + col0 + cbase + ni * 16 + l15] = f2fp8(acc[mi][ni][reg]);
            }
        }

    // ---- fused alpha epilogue (fp32-exact from accumulators) ----
    const int hd = (col0 + cbase) >> 6;
    float aS[4], aD[4];
    #pragma unroll
    for (int ni = 0; ni < 4; ++ni) {
        aS[ni] = a_src[hd * 64 + ni * 16 + l15];
        aD[ni] = a_dst[hd * 64 + ni * 16 + l15];
    }
    #pragma unroll
    for (int mi = 0; mi < MI; ++mi)
        #pragma unroll
        for (int reg = 0; reg < 4; ++reg) {
            float s = 0.f, d = 0.f;
            #pragma unroll
            for (int ni = 0; ni < 4; ++ni) {
                s += acc[mi][ni][reg] * aS[ni];
                d += acc[mi][ni][reg] * aD[ni];
            }
            #pragma unroll
            for (int off = 1; off < 16; off <<= 1) {
                s += __shfl_xor(s, off);
                d += __shfl_xor(d, off);
            }
            int gr = row0 + rbase + mi * 16 + l4 * 4 + reg;
            if (l15 == 0 && gr < M) {
                asrc[gr * H + hd] = s;
                adst[gr * H + hd] = d;
            }
        }
}

// ---------------------------------------------------------------------------
// Aggregate, H=4: ONE wave per node; h fp8 [N][256] (256B rows); bf16 out.
// ---------------------------------------------------------------------------
__global__ __launch_bounds__(256)
void aggregate4_kernel(const uchar_t* __restrict__ h, const float* __restrict__ asrc,
                       const float* __restrict__ adst, const int* __restrict__ indptr,
                       const int* __restrict__ csr_src, const float* __restrict__ bias,
                       ushort_t* __restrict__ out, int n, int apply_elu) {
    __shared__ int   sOff[4][64];
    __shared__ float sEx[4][4][68];
    const int node = (blockIdx.x * blockDim.x + threadIdx.x) >> 6;
    const int lane = threadIdx.x & 63;
    const int w    = threadIdx.x >> 6;
    if (node >= n) return;
    const int hd   = lane >> 4;
    const int eidx = lane & 15;
    const int beg = indptr[node], end = indptr[node + 1];
    const float ad = adst[node * 4 + hd];
    const uchar_t* __restrict__ hrow = h + 4 * lane;   // 4 fp8 channels per lane

    float sum_ex = 0.f;
    float ax = 0.f, ay = 0.f, az = 0.f, aw = 0.f;
    for (int cb = beg; cb < end; cb += 64) {
        const int cnt = min(64, end - cb);
        // ---- pass A ----
        int s[4];
        float ex[4];
        #pragma unroll
        for (int j = 0; j < 4; ++j) {
            int idx = eidx + 16 * j;
            s[j] = (idx < cnt) ? csr_src[cb + idx] : 0;
        }
        #pragma unroll
        for (int j = 0; j < 4; ++j) {
            float t = asrc[s[j] * 4 + hd] + ad;
            t = t > 0.f ? t : NEG_SLOPE * t;
            ex[j] = (eidx + 16 * j < cnt) ? __expf(t) : 0.f;
        }
        float csum = (ex[0] + ex[1]) + (ex[2] + ex[3]);
        #pragma unroll
        for (int off = 1; off < 16; off <<= 1) csum += __shfl_xor(csum, off);
        sum_ex += csum;
        #pragma unroll
        for (int j = 0; j < 4; ++j) sEx[w][hd][eidx + 16 * j] = ex[j];
        if (hd == 0) {
            #pragma unroll
            for (int j = 0; j < 4; ++j) sOff[w][eidx + 16 * j] = s[j] << 8;  // byte offset
        }
        // ---- pass B: gather fp8 rows (uint per lane), 8 in flight ----
        int i = 0;
        for (; i + 8 <= cnt; i += 8) {
            int o[8];
            float ee[8];
            unsigned v[8];
            #pragma unroll
            for (int u = 0; u < 8; ++u) o[u] = sOff[w][i + u];
            #pragma unroll
            for (int u = 0; u < 8; ++u) v[u] = *reinterpret_cast<const unsigned*>(hrow + o[u]);
            #pragma unroll
            for (int u = 0; u < 8; ++u) ee[u] = sEx[w][hd][i + u];
            #pragma unroll
            for (int u = 0; u < 8; ++u) {
                f32x2 lo = __builtin_amdgcn_cvt_pk_f32_fp8((int)v[u], false);
                f32x2 hi = __builtin_amdgcn_cvt_pk_f32_fp8((int)v[u], true);
                ax += ee[u] * lo[0];
                ay += ee[u] * lo[1];
                az += ee[u] * hi[0];
                aw += ee[u] * hi[1];
            }
        }
        for (; i < cnt; ++i) {
            int o = sOff[w][i];
            float ee = sEx[w][hd][i];
            unsigned v = *reinterpret_cast<const unsigned*>(hrow + o);
            f32x2 lo = __builtin_amdgcn_cvt_pk_f32_fp8((int)v, false);
            f32x2 hi = __builtin_amdgcn_cvt_pk_f32_fp8((int)v, true);
            ax += ee * lo[0]; ay += ee * lo[1];
            az += ee * hi[0]; aw += ee * hi[1];
        }
    }
    const float inv = 1.f / (sum_ex + EPSV);
    float4 b4 = *reinterpret_cast<const float4*>(bias + 4 * lane);
    float ox = ax * inv + b4.x;
    float oy = ay * inv + b4.y;
    float oz = az * inv + b4.z;
    float ow = aw * inv + b4.w;
    if (apply_elu) {
        ox = ox > 0.f ? ox : expm1f(ox);
        oy = oy > 0.f ? oy : expm1f(oy);
        oz = oz > 0.f ? oz : expm1f(oz);
        ow = ow > 0.f ? ow : expm1f(ow);
    }
    ushort4 o4;
    o4.x = f2bf(ox); o4.y = f2bf(oy); o4.z = f2bf(oz); o4.w = f2bf(ow);
    *reinterpret_cast<ushort4*>(out + (long)node * 256 + 4 * lane) = o4;
}

// ---------------------------------------------------------------------------
// Aggregate, H=1: wave = 64 lanes = channels; h fp8 [N][64]; bf16 out.
// ---------------------------------------------------------------------------
__global__ __launch_bounds__(256)
void aggregate_kernel(const uchar_t* __restrict__ h, const float* __restrict__ asrc,
                      const float* __restrict__ adst, const int* __restrict__ indptr,
                      const int* __restrict__ csr_src, const float* __restrict__ bias,
                      ushort_t* __restrict__ out, int n, int apply_elu) {
    __shared__ int   sInd[4][64];
    __shared__ float sEx[4][64];
    const int node = (blockIdx.x * blockDim.x + threadIdx.x) >> 6;
    const int lane = threadIdx.x & 63;
    const int w    = threadIdx.x >> 6;
    if (node >= n) return;
    const int beg = indptr[node];
    const int end = indptr[node + 1];
    const float ad = adst[node];
    const uchar_t* __restrict__ hh = h + lane;

    float sum_ex = 0.f, acc = 0.f;
    for (int cb = beg; cb < end; cb += 64) {
        const int cnt = min(64, end - cb);
        int s = 0;
        float ex = 0.f;
        if (lane < cnt) {
            s = csr_src[cb + lane];
            float e = asrc[s] + ad;
            e = e > 0.f ? e : NEG_SLOPE * e;
            ex = __expf(e);
        }
        float cs = ex;
        #pragma unroll
        for (int off = 32; off > 0; off >>= 1) cs += __shfl_xor(cs, off);
        sum_ex += cs;
        sInd[w][lane] = s;
        sEx[w][lane]  = ex;
        int i = 0;
        for (; i + 8 <= cnt; i += 8) {
            int si[8];
            float ei_[8], vi[8];
            #pragma unroll
            for (int u = 0; u < 8; ++u) si[u] = sInd[w][i + u];
            #pragma unroll
            for (int u = 0; u < 8; ++u) {
                unsigned b = hh[(long)si[u] * 64];
                f32x2 r = __builtin_amdgcn_cvt_pk_f32_fp8((int)b, false);
                vi[u] = r[0];
            }
            #pragma unroll
            for (int u = 0; u < 8; ++u) ei_[u] = sEx[w][i + u];
            #pragma unroll
            for (int u = 0; u < 8; ++u) acc += ei_[u] * vi[u];
        }
        for (; i < cnt; ++i) {
            unsigned b = hh[(long)sInd[w][i] * 64];
            f32x2 r = __builtin_amdgcn_cvt_pk_f32_fp8((int)b, false);
            acc += sEx[w][i] * r[0];
        }
    }
    float o = acc / (sum_ex + EPSV) + bias[lane];
    if (apply_elu) o = o > 0.f ? o : expm1f(o);
    out[(long)node * 64 + lane] = f2bf(o);
}

// ---------------------------------------------------------------------------
// Global mean pool (batch is sorted, bf16 input) + classifier
// ---------------------------------------------------------------------------
constexpr int POOL_CHUNK = 128;

__global__ __launch_bounds__(64)
void pool_kernel(const ushort_t* __restrict__ h, const int* __restrict__ batch,
                 float* __restrict__ sums, int* __restrict__ counts, int n) {
    int lane = threadIdx.x;
    int start = blockIdx.x * POOL_CHUNK;
    if (start >= n) return;
    int end = min(start + POOL_CHUNK, n);
    int gcur = batch[start];
    float acc = 0.f;
    int run = 0;
    for (int i = start; i < end; ++i) {
        int g = batch[i];
        if (g != gcur) {
            atomicAdd(&sums[gcur * 64 + lane], acc);
            if (lane == 0) atomicAdd(&counts[gcur], run);
            acc = 0.f; run = 0; gcur = g;
        }
        acc += bf2f(h[(long)i * 64 + lane]);
        ++run;
    }
    atomicAdd(&sums[gcur * 64 + lane], acc);
    if (lane == 0) atomicAdd(&counts[gcur], run);
}

__global__ void classify_kernel(const float* __restrict__ sums, const int* __restrict__ counts,
                                const float* __restrict__ Wc, const float* __restrict__ bc,
                                float* __restrict__ out, int G) {
    int t = threadIdx.x;
    if (t >= G * 10) return;
    int g = t / 10, o = t - g * 10;
    int c_ = counts[g];
    float inv = 1.f / (float)(c_ > 1 ? c_ : 1);
    float acc = bc[o];
    for (int c = 0; c < 64; ++c)
        acc += sums[g * 64 + c] * inv * Wc[c * 10 + o];
    out[t] = acc;
}

// ---------------------------------------------------------------------------
extern "C" void kernel_launch(void* const* d_in, const int* in_sizes, int n_in,
                              void* d_out, int out_size, void* d_ws, size_t ws_size,
                              hipStream_t stream) {
    const float* x   = (const float*)d_in[0];
    const int*   ei  = (const int*)d_in[1];
    const int*   bat = (const int*)d_in[2];
    const float* W1  = (const float*)d_in[3];
    const float* as1 = (const float*)d_in[4];
    const float* ad1 = (const float*)d_in[5];
    const float* b1  = (const float*)d_in[6];
    const float* W2  = (const float*)d_in[7];
    const float* as2 = (const float*)d_in[8];
    const float* ad2 = (const float*)d_in[9];
    const float* b2  = (const float*)d_in[10];
    const float* W3  = (const float*)d_in[11];
    const float* as3 = (const float*)d_in[12];
    const float* ad3 = (const float*)d_in[13];
    const float* b3  = (const float*)d_in[14];
    const float* Wc  = (const float*)d_in[15];
    const float* bc  = (const float*)d_in[16];
    float* out = (float*)d_out;

    const int N = in_sizes[2];          // 50000 nodes
    const int E = in_sizes[1] / 2;      // 800000 edges
    const int M = E + N;                // + self loops
    const int IN_C = in_sizes[0] / N;   // 128
    const int G = out_size / 10;        // 64 graphs

    // -------- workspace carve (256B aligned) --------
    char* p = (char*)d_ws;
    auto carve = [&](size_t bytes) -> void* {
        void* r = (void*)p;
        p += (bytes + 255) & ~(size_t)255;
        return r;
    };
    uchar_t*  hA  = (uchar_t*)carve((size_t)N * 256);       // fp8 gather table
    ushort_t* hB  = (ushort_t*)carve((size_t)N * 256 * 2);  // bf16 activations
    ushort_t* xb  = (ushort_t*)carve((size_t)N * IN_C * 2);
    ushort_t* Wt1 = (ushort_t*)carve((size_t)256 * IN_C * 2);
    ushort_t* Wt2 = (ushort_t*)carve((size_t)256 * 256 * 2);
    ushort_t* Wt3 = (ushort_t*)carve((size_t)64 * 256 * 2);
    float* asrc = (float*)carve((size_t)N * 4 * 4);
    float* adst = (float*)carve((size_t)N * 4 * 4);
    float* sums = (float*)carve((size_t)G * 64 * 4 + (size_t)G * 4);  // sums + cnts contiguous
    int*   cnts = (int*)(sums + (size_t)G * 64);
    int*   deg  = (int*)carve((size_t)N * 4);   // also scatter cursor
    int*   iptr = (int*)carve((size_t)(N + 1) * 4);
    int*   csr  = (int*)carve((size_t)M * 4);
    int*   bsum = (int*)carve(256 * 4);
    (void)ws_size; (void)n_in;

    const int NB = (N + 1023) / 1024;

    // -------- prep (cvt + 3x transW + deg zero, one kernel) --------
    {
        long nx4 = (long)N * IN_C / 4;
        long total = nx4 + (long)IN_C * 256 + 256 * 256 + 256 * 64 + N;
        prep_kernel<<<(int)((total + 255) / 256), 256, 0, stream>>>(
            x, xb, (int)nx4, W1, Wt1, W2, Wt2, W3, Wt3, IN_C, deg, N);
    }

    // -------- CSR build (shared by all 3 layers) --------
    count_kernel<<<(M + 255) / 256, 256, 0, stream>>>(ei, deg, E, N);
    scan1_kernel<<<NB, 1024, 0, stream>>>(deg, iptr, bsum, N);
    scan3_kernel<<<NB, 1024, 0, stream>>>(iptr, deg, bsum, NB, N);  // deg becomes cursor
    scatter_kernel<<<(M + 255) / 256, 256, 0, stream>>>(ei, deg, csr, E, N);

    // -------- layer 1: xb[N,128] -> hB[N,256] --------
    {
        dim3 grid((N + 127) / 128, 2);
        mfma_gemm_alpha_kernel<2><<<grid, 256, 0, stream>>>(xb, Wt1, hA, as1, ad1,
                                                            asrc, adst, N, IN_C, 256, 4);
    }
    aggregate4_kernel<<<(N + 3) / 4, 256, 0, stream>>>(hA, asrc, adst, iptr, csr, b1, hB, N, 1);

    // -------- layer 2: hB[N,256] -> hB[N,256] --------
    {
        dim3 grid((N + 127) / 128, 2);
        mfma_gemm_alpha_kernel<2><<<grid, 256, 0, stream>>>(hB, Wt2, hA, as2, ad2,
                                                            asrc, adst, N, 256, 256, 4);
    }
    aggregate4_kernel<<<(N + 3) / 4, 256, 0, stream>>>(hA, asrc, adst, iptr, csr, b2, hB, N, 1);

    // -------- layer 3: hB[N,256] -> hA[N,64] fp8 (1 head, no ELU) --------
    {
        dim3 grid((N + 127) / 128, 1);
        mfma_gemm_alpha_kernel<1><<<grid, 256, 0, stream>>>(hB, Wt3, hA, as3, ad3,
                                                            asrc, adst, N, 256, 64, 1);
    }
    aggregate_kernel<<<(N + 3) / 4, 256, 0, stream>>>(hA, asrc, adst, iptr, csr, b3, hB, N, 0);

    // -------- pool + classify --------
    hipMemsetAsync(sums, 0, (size_t)G * 64 * 4 + (size_t)G * 4, stream);
    pool_kernel<<<(N + POOL_CHUNK - 1) / POOL_CHUNK, 64, 0, stream>>>(hB, bat, sums, cnts, N);
    classify_kernel<<<1, 640, 0, stream>>>(sums, cnts, Wc, bc, out, G);
}